// Round 7
// baseline (10292.044 us; speedup 1.0000x reference)
//
#include <hip/hip_runtime.h>
#include <stdint.h>

// ---------- types / helpers ----------
typedef short bf16x8 __attribute__((ext_vector_type(8)));   // 8 bf16 = 4 VGPR (MFMA A/B frag)
typedef float f32x4  __attribute__((ext_vector_type(4)));   // MFMA C/D frag

__device__ __forceinline__ unsigned short f2bf(float x) {
  unsigned int u = __builtin_bit_cast(unsigned int, x);
  u += 0x7fffu + ((u >> 16) & 1u);
  return (unsigned short)(u >> 16);
}
__device__ __forceinline__ float bf2f(unsigned short b) {
  unsigned int u = ((unsigned int)b) << 16;
  return __builtin_bit_cast(float, u);
}
__device__ __forceinline__ f32x4 mfma16(bf16x8 a, bf16x8 b, f32x4 c) {
  return __builtin_amdgcn_mfma_f32_16x16x32_bf16(a, b, c, 0, 0, 0);
}
// load 8 consecutive f32, split into hi/lo bf16 (hi+lo ~ f32-exact)
__device__ __forceinline__ void split8(const float* __restrict__ p, bf16x8* h, bf16x8* l) {
  float4 a = *reinterpret_cast<const float4*>(p);
  float4 b = *reinterpret_cast<const float4*>(p + 4);
  float v[8] = {a.x, a.y, a.z, a.w, b.x, b.y, b.z, b.w};
  bf16x8 hh, ll;
#pragma unroll
  for (int i = 0; i < 8; ++i) {
    unsigned short hb = f2bf(v[i]);
    hh[i] = (short)hb;
    ll[i] = (short)f2bf(v[i] - bf2f(hb));
  }
  *h = hh; *l = ll;
}
__device__ __forceinline__ float fexp(float x) {  // e^x via v_exp_f32
  return __builtin_amdgcn_exp2f(x * 1.4426950408889634f);
}
__device__ __forceinline__ float sigm(float x) {
  return __builtin_amdgcn_rcpf(1.f + fexp(-x));
}
__device__ __forceinline__ float tanh_fast(float x) {
  x = fminf(fmaxf(x, -15.f), 15.f);
  float e2 = fexp(2.f * x);
  return (e2 - 1.f) * __builtin_amdgcn_rcpf(e2 + 1.f);
}

// ---------- weight prep: split f32 weights into frag-ordered bf16 hi/lo (once) ----------
// gGl layout (ushort): ihH[0,24576) ihL[24576,49152) hhH[49152,61440) hhL[61440,73728)
// gGc layout:          ihH[0,12288) ihL[12288,24576) hhH[24576,36864) hhL[36864,49152)
// gMl/gMc layout:      W1H[0,4096)  W1L[4096,8192)   W2H[8192,12288)  W2L[12288,16384)
__global__ void prep_split(const float* __restrict__ glWih, const float* __restrict__ glWhh,
                           const float* __restrict__ gcWih, const float* __restrict__ gcWhh,
                           const float* __restrict__ mlW1, const float* __restrict__ mlW2,
                           const float* __restrict__ mcW1, const float* __restrict__ mcW2,
                           unsigned short* __restrict__ gGl, unsigned short* __restrict__ gGc,
                           unsigned short* __restrict__ gMl, unsigned short* __restrict__ gMc) {
  int b = blockIdx.x, t = threadIdx.x;
  const float* src; unsigned short *dh, *dl; int NT, KX;
  switch (b) {
    case 0: src = glWih; dh = gGl;         dl = gGl + 24576; NT = 12; KX = 128; break;
    case 1: src = glWhh; dh = gGl + 49152; dl = gGl + 61440; NT = 12; KX = 64;  break;
    case 2: src = gcWih; dh = gGc;         dl = gGc + 12288; NT = 12; KX = 64;  break;
    case 3: src = gcWhh; dh = gGc + 24576; dl = gGc + 36864; NT = 12; KX = 64;  break;
    case 4: src = mlW1;  dh = gMl;         dl = gMl + 4096;  NT = 4;  KX = 64;  break;
    case 5: src = mlW2;  dh = gMl + 8192;  dl = gMl + 12288; NT = 4;  KX = 64;  break;
    case 6: src = mcW1;  dh = gMc;         dl = gMc + 4096;  NT = 4;  KX = 64;  break;
    default: src = mcW2; dh = gMc + 8192;  dl = gMc + 12288; NT = 4;  KX = 64;  break;
  }
  int NKC = KX / 32;
  int tot = NT * NKC * 64;
  for (int e = t; e < tot; e += 256) {
    int f = e >> 6, l = e & 63;
    int nt = f / NKC, kc = f % NKC;
    int n = nt * 16 + (l & 15), k0 = kc * 32 + (l >> 4) * 8;
    bf16x8 h, lo;
    split8(src + n * KX + k0, &h, &lo);
    *reinterpret_cast<bf16x8*>(dh + e * 8) = h;
    *reinterpret_cast<bf16x8*>(dl + e * 8) = lo;
  }
}

// ---------- fused 2x MLP (grid split), operand-swapped MFMA: D = W·X^T ----------
// lane holds one x-row (lane&15) and 4 consecutive n-cols ((lane>>4)*4+i) -> float4 stores.
__global__ __launch_bounds__(256, 3) void mlp_kernel(
    const float* __restrict__ X1, float* __restrict__ Y1, int T1,
    const unsigned short* __restrict__ g1, const float* __restrict__ B11, const float* __restrict__ B21,
    const float* __restrict__ X2, float* __restrict__ Y2, int T2,
    const unsigned short* __restrict__ g2, const float* __restrict__ B12, const float* __restrict__ B22,
    int G1) {
  const float* X; float* Y; int tiles, b, nb;
  const unsigned short* gw; const float *B1, *B2;
  if ((int)blockIdx.x < G1) {
    X = X1; Y = Y1; tiles = T1; gw = g1; B1 = B11; B2 = B21; b = blockIdx.x; nb = G1;
  } else {
    X = X2; Y = Y2; tiles = T2; gw = g2; B1 = B12; B2 = B22; b = blockIdx.x - G1; nb = gridDim.x - G1;
  }
  __shared__ __align__(16) unsigned short wbuf[16384];
  __shared__ __align__(16) float hbuf[4][16 * 68];
  int tid = threadIdx.x, wid = tid >> 6, lane = tid & 63;
  int r = lane & 15, kb = lane >> 4;
  for (int i4 = tid; i4 < 2048; i4 += 256)
    *reinterpret_cast<int4*>(wbuf + i4 * 8) = *reinterpret_cast<const int4*>(gw + i4 * 8);
  __syncthreads();
  const unsigned short *w1h = wbuf, *w1l = wbuf + 4096, *w2h = wbuf + 8192, *w2l = wbuf + 12288;
  f32x4 b1f[4], b2f[4];
#pragma unroll
  for (int nt = 0; nt < 4; ++nt) {
    b1f[nt] = *reinterpret_cast<const f32x4*>(B1 + nt * 16 + kb * 4);
    b2f[nt] = *reinterpret_cast<const f32x4*>(B2 + nt * 16 + kb * 4);
  }
  float* hl = hbuf[wid];
  for (int t = b * 4 + wid; t < tiles; t += nb * 4) {
    int row0 = t << 4;
    const float* xp = X + (size_t)(row0 + r) * 64 + kb * 8;
    bf16x8 a0h, a0l, a1h, a1l;
    split8(xp, &a0h, &a0l);
    split8(xp + 32, &a1h, &a1l);
#pragma unroll
    for (int nt = 0; nt < 4; ++nt) {
      f32x4 c = b1f[nt];
      bf16x8 wh = *reinterpret_cast<const bf16x8*>(w1h + ((nt * 2 + 0) * 64 + lane) * 8);
      bf16x8 wl = *reinterpret_cast<const bf16x8*>(w1l + ((nt * 2 + 0) * 64 + lane) * 8);
      c = mfma16(wh, a0l, c); c = mfma16(wl, a0h, c); c = mfma16(wh, a0h, c);
      wh = *reinterpret_cast<const bf16x8*>(w1h + ((nt * 2 + 1) * 64 + lane) * 8);
      wl = *reinterpret_cast<const bf16x8*>(w1l + ((nt * 2 + 1) * 64 + lane) * 8);
      c = mfma16(wh, a1l, c); c = mfma16(wl, a1h, c); c = mfma16(wh, a1h, c);
#pragma unroll
      for (int i = 0; i < 4; ++i) c[i] = fmaxf(c[i], 0.f);
      *reinterpret_cast<f32x4*>(hl + r * 68 + nt * 16 + kb * 4) = c;  // b128 write, own row
    }
    // same-wave LDS RAW: DS pipe is in-order within a wave
    bf16x8 h0h, h0l, h1h, h1l;
    split8(hl + r * 68 + kb * 8, &h0h, &h0l);
    split8(hl + r * 68 + 32 + kb * 8, &h1h, &h1l);
    float* yp = Y + (size_t)row0 * 64;
#pragma unroll
    for (int nt = 0; nt < 4; ++nt) {
      f32x4 c = b2f[nt];
      bf16x8 wh = *reinterpret_cast<const bf16x8*>(w2h + ((nt * 2 + 0) * 64 + lane) * 8);
      bf16x8 wl = *reinterpret_cast<const bf16x8*>(w2l + ((nt * 2 + 0) * 64 + lane) * 8);
      c = mfma16(wh, h0l, c); c = mfma16(wl, h0h, c); c = mfma16(wh, h0h, c);
      wh = *reinterpret_cast<const bf16x8*>(w2h + ((nt * 2 + 1) * 64 + lane) * 8);
      wl = *reinterpret_cast<const bf16x8*>(w2l + ((nt * 2 + 1) * 64 + lane) * 8);
      c = mfma16(wh, h1l, c); c = mfma16(wl, h1h, c); c = mfma16(wh, h1h, c);
      *reinterpret_cast<f32x4*>(yp + (size_t)r * 64 + nt * 16 + kb * 4) = c;  // float4 store
    }
  }
}

// ---------- GRU cell, in place, hi/lo 3-term, swapped MFMA, LDS weights, persistent ----------
// 1024 threads, EXACTLY 4 waves/EU forced -> 128 VGPR budget, no spill, 16 waves/CU.
template <int KX>
__global__ __attribute__((amdgpu_flat_work_group_size(1024, 1024), amdgpu_waves_per_eu(4, 4)))
void gru_kernel(
    const float* __restrict__ Xa, float* __restrict__ H,
    const unsigned short* __restrict__ gws,
    const float* __restrict__ Bih, const float* __restrict__ Bhh, int M) {
  constexpr int NKC_X = KX / 32;
  constexpr int NFX = 12 * NKC_X;
  constexpr int IHL = NFX * 512;       // ihL offset (ushorts)
  constexpr int HH0 = 2 * NFX * 512;   // hhH
  constexpr int HHL = HH0 + 12288;     // hhL
  constexpr int TOTU = HH0 + 24576;
  __shared__ __align__(16) unsigned short wlds[TOTU];
  __shared__ __align__(16) float ldsB[256];  // [0,64) r-sum [64,128) z-sum [128,192) bnI [192,256) bnH
  int tid = threadIdx.x;
  for (int i4 = tid; i4 < TOTU / 8; i4 += 1024)
    *reinterpret_cast<int4*>(wlds + i4 * 8) = *reinterpret_cast<const int4*>(gws + i4 * 8);
  if (tid < 128) ldsB[tid] = Bih[tid] + Bhh[tid];
  else if (tid < 192) ldsB[tid] = Bih[tid];            // bnI: Bih[128+j] at ldsB[128+j]
  else if (tid < 256) ldsB[tid] = Bhh[tid - 64];       // bnH: Bhh[128+j] at ldsB[192+j]
  __syncthreads();
  int wid = tid >> 6, lane = tid & 63;
  int r = lane & 15, kb = lane >> 4;
  int tiles = M >> 4;
  for (int t = blockIdx.x * 16 + wid; t < tiles; t += gridDim.x * 16) {
    int row0 = t << 4;
    bf16x8 axh[NKC_X], axl[NKC_X], ahh[2], ahl[2];
#pragma unroll
    for (int kc = 0; kc < 2; ++kc)
      split8(Xa + (size_t)(row0 + r) * 64 + kc * 32 + kb * 8, &axh[kc], &axl[kc]);
    if (KX == 128) {
#pragma unroll
      for (int kc = 0; kc < 2; ++kc)  // pair-flip lives inside this 16-row tile
        split8(H + (size_t)((row0 + r) ^ 1) * 64 + kc * 32 + kb * 8, &axh[2 + kc], &axl[2 + kc]);
    }
#pragma unroll
    for (int kc = 0; kc < 2; ++kc)
      split8(H + (size_t)(row0 + r) * 64 + kc * 32 + kb * 8, &ahh[kc], &ahl[kc]);

    auto dot_ih = [&](int nt) -> f32x4 {
      f32x4 c; c[0] = c[1] = c[2] = c[3] = 0.f;
#pragma unroll
      for (int kc = 0; kc < NKC_X; ++kc) {
        bf16x8 wh = *reinterpret_cast<const bf16x8*>(wlds + (nt * NKC_X + kc) * 512 + lane * 8);
        bf16x8 wl = *reinterpret_cast<const bf16x8*>(wlds + IHL + (nt * NKC_X + kc) * 512 + lane * 8);
        c = mfma16(wh, axl[kc], c);
        c = mfma16(wl, axh[kc], c);
        c = mfma16(wh, axh[kc], c);
      }
      return c;
    };
    auto dot_hh = [&](int nt) -> f32x4 {
      f32x4 c; c[0] = c[1] = c[2] = c[3] = 0.f;
#pragma unroll
      for (int kc = 0; kc < 2; ++kc) {
        bf16x8 wh = *reinterpret_cast<const bf16x8*>(wlds + HH0 + (nt * 2 + kc) * 512 + lane * 8);
        bf16x8 wl = *reinterpret_cast<const bf16x8*>(wlds + HHL + (nt * 2 + kc) * 512 + lane * 8);
        c = mfma16(wh, ahl[kc], c);
        c = mfma16(wl, ahh[kc], c);
        c = mfma16(wh, ahh[kc], c);
      }
      return c;
    };

#pragma unroll
    for (int q = 0; q < 4; ++q) {
      f32x4 pr = dot_ih(q);     f32x4 qr = dot_hh(q);
      f32x4 pz = dot_ih(q + 4); f32x4 qz = dot_hh(q + 4);
      f32x4 pn = dot_ih(q + 8); f32x4 qn = dot_hh(q + 8);
      int cb = q * 16 + kb * 4;  // 4 consecutive H columns owned by this lane
      f32x4 bR = *reinterpret_cast<const f32x4*>(ldsB + cb);
      f32x4 bZ = *reinterpret_cast<const f32x4*>(ldsB + 64 + cb);
      f32x4 bI = *reinterpret_cast<const f32x4*>(ldsB + 128 + cb);
      f32x4 bH = *reinterpret_cast<const f32x4*>(ldsB + 192 + cb);
      float* hp = H + (size_t)(row0 + r) * 64 + cb;
      f32x4 hv = *reinterpret_cast<const f32x4*>(hp);
      f32x4 hn;
#pragma unroll
      for (int i = 0; i < 4; ++i) {
        float rg = sigm(pr[i] + qr[i] + bR[i]);
        float zg = sigm(pz[i] + qz[i] + bZ[i]);
        float tn = tanh_fast(pn[i] + bI[i] + rg * (qn[i] + bH[i]));
        hn[i] = (1.f - zg) * tn + zg * hv[i];
      }
      *reinterpret_cast<f32x4*>(hp) = hn;  // aligned float4 store
    }
  }
}

// ---------- fused 2x CSR gather aggregation (grid split over dst ranges) ----------
__global__ __launch_bounds__(256, 6) void aggr_kernel(
    const float* __restrict__ msgA, const int* __restrict__ rpA,
    const int* __restrict__ srcA, float* __restrict__ outA, int NA,
    const float* __restrict__ msgB, const int* __restrict__ rpB,
    const int* __restrict__ srcB, float* __restrict__ outB, int NB) {
  int gtid = blockIdx.x * 256 + threadIdx.x;
  int w = gtid >> 6, lane = gtid & 63;
  int nw = gridDim.x * 4;
  int tot = NA + NB;
  for (int d = w; d < tot; d += nw) {
    const float* msg; const int* rp; const int* srcv; float* out; int dst;
    if (d < NA) { msg = msgA; rp = rpA; srcv = srcA; out = outA; dst = d; }
    else        { msg = msgB; rp = rpB; srcv = srcB; out = outB; dst = d - NA; }
    int p0 = rp[dst], p1 = rp[dst + 1];
    float acc = 0.f;
    int j = p0;
    for (; j + 8 <= p1; j += 8) {
      int s0 = srcv[j],     s1 = srcv[j + 1], s2 = srcv[j + 2], s3 = srcv[j + 3];
      int s4 = srcv[j + 4], s5 = srcv[j + 5], s6 = srcv[j + 6], s7 = srcv[j + 7];
      float a0 = msg[(size_t)s0 * 64 + lane];
      float a1 = msg[(size_t)s1 * 64 + lane];
      float a2 = msg[(size_t)s2 * 64 + lane];
      float a3 = msg[(size_t)s3 * 64 + lane];
      float a4 = msg[(size_t)s4 * 64 + lane];
      float a5 = msg[(size_t)s5 * 64 + lane];
      float a6 = msg[(size_t)s6 * 64 + lane];
      float a7 = msg[(size_t)s7 * 64 + lane];
      acc += a0; acc += a1; acc += a2; acc += a3;
      acc += a4; acc += a5; acc += a6; acc += a7;
    }
    for (; j < p1; ++j) acc += msg[(size_t)srcv[j] * 64 + lane];
    out[(size_t)dst * 64 + lane] = acc;
  }
}

// ---------- CSR build ----------
__global__ void count_kernel(const int* __restrict__ le, const int* __restrict__ ce,
                             int* __restrict__ degL, int* __restrict__ degC, int E) {
  for (int e = blockIdx.x * 256 + threadIdx.x; e < E; e += gridDim.x * 256) {
    atomicAdd(&degL[le[e]], 1);
    atomicAdd(&degC[ce[e]], 1);
  }
}
__global__ void scan_pass1(const int* __restrict__ in, int* __restrict__ bsum, int N, int chunk) {
  int b = blockIdx.x, t = threadIdx.x;
  int base = b * chunk;
  int seg = (chunk + 255) >> 8;
  int a = base + t * seg;
  int e = min(min(N, base + chunk), a + seg);
  int s = 0;
  for (int i = a; i < e; ++i) s += in[i];
  __shared__ int red[256];
  red[t] = s; __syncthreads();
  for (int off = 128; off > 0; off >>= 1) {
    if (t < off) red[t] += red[t + off];
    __syncthreads();
  }
  if (t == 0) bsum[b] = red[0];
}
__global__ void scan_pass2(int* bsum, int* totalOut) {
  __shared__ int sc[256];
  int t = threadIdx.x;
  int v = bsum[t];
  sc[t] = v; __syncthreads();
  for (int off = 1; off < 256; off <<= 1) {
    int u = (t >= off) ? sc[t - off] : 0;
    __syncthreads();
    sc[t] += u;
    __syncthreads();
  }
  bsum[t] = sc[t] - v;
  if (t == 255) *totalOut = sc[255];
}
__global__ void scan_pass3(const int* __restrict__ in, const int* __restrict__ bsum,
                           int* __restrict__ outp, int N, int chunk) {
  int b = blockIdx.x, t = threadIdx.x;
  int base = b * chunk;
  int seg = (chunk + 255) >> 8;
  int a = base + t * seg;
  int e = min(min(N, base + chunk), a + seg);
  int s = 0;
  for (int i = a; i < e; ++i) s += in[i];
  __shared__ int sc[256];
  int v = s;
  sc[t] = v; __syncthreads();
  for (int off = 1; off < 256; off <<= 1) {
    int u = (t >= off) ? sc[t - off] : 0;
    __syncthreads();
    sc[t] += u;
    __syncthreads();
  }
  int run = bsum[b] + sc[t] - v;
  for (int i = a; i < e; ++i) { outp[i] = run; run += in[i]; }
}
__global__ void fill_kernel(const int* __restrict__ le, const int* __restrict__ ce,
                            int* __restrict__ curL, int* __restrict__ curC,
                            int* __restrict__ srcL2C, int* __restrict__ srcC2L, int E) {
  for (int e = blockIdx.x * 256 + threadIdx.x; e < E; e += gridDim.x * 256) {
    int ls = le[e], cd = ce[e];
    int s1 = atomicAdd(&curC[cd], 1);
    srcL2C[s1] = ls;
    int s2 = atomicAdd(&curL[ls], 1);
    srcC2L[s2] = cd;
  }
}

// ---------- init / readout ----------
__global__ void init_emb(float* __restrict__ emb, const float* __restrict__ ini, int n) {
  for (int i = blockIdx.x * 256 + threadIdx.x; i < n; i += gridDim.x * 256)
    emb[i] = ini[i & 63];
}
__global__ void readout_sum(const float* __restrict__ lemb, const int* __restrict__ lb,
                            float* __restrict__ gsum, float* __restrict__ gcnt, int L) {
  int gtid = blockIdx.x * 256 + threadIdx.x;
  int w = gtid >> 6, lane = gtid & 63;
  int nw = gridDim.x * 4;
  int chunk = (L + nw - 1) / nw;
  int s = w * chunk, e = min(L, s + chunk);
  if (s >= e) return;
  float acc = 0.f, cnt = 0.f;
  int curb = lb[s];
  for (int row = s; row < e; ++row) {
    int b = lb[row];
    if (b != curb) {
      atomicAdd(&gsum[curb * 64 + lane], acc);
      if (lane == 0) atomicAdd(&gcnt[curb], cnt);
      acc = 0.f; cnt = 0.f; curb = b;
    }
    acc += lemb[(size_t)row * 64 + lane];
    cnt += 1.f;
  }
  atomicAdd(&gsum[curb * 64 + lane], acc);
  if (lane == 0) atomicAdd(&gcnt[curb], cnt);
}
__global__ void final_kernel(const float* __restrict__ gsum, const float* __restrict__ gcnt,
                             const float* __restrict__ W1, const float* __restrict__ B1,
                             const float* __restrict__ W2, const float* __restrict__ B2,
                             float* __restrict__ outp) {
  __shared__ float w1s[4096];
  __shared__ float w2s[64];
  int t = threadIdx.x;  // 128 threads: one per graph
  for (int i = t; i < 4096; i += 128) w1s[i] = W1[i];
  if (t < 64) w2s[t] = W2[t];
  __syncthreads();
  float x[64];
  float c = fmaxf(gcnt[t], 1.f);
#pragma unroll
  for (int d = 0; d < 64; ++d) x[d] = gsum[t * 64 + d] / c;
  float acc = B2[0];
  for (int j = 0; j < 64; ++j) {
    float h = B1[j];
#pragma unroll
    for (int k = 0; k < 64; ++k) h += x[k] * w1s[j * 64 + k];
    acc += fmaxf(h, 0.f) * w2s[j];
  }
  outp[t] = 1.f / (1.f + __expf(-acc));
}

// ---------- launch ----------
extern "C" void kernel_launch(void* const* d_in, const int* in_sizes, int n_in,
                              void* d_out, int out_size, void* d_ws, size_t ws_size,
                              hipStream_t stream) {
  const int* le = (const int*)d_in[2];
  const int* ce = (const int*)d_in[3];
  const int* lb = (const int*)d_in[4];
  const float* l_init = (const float*)d_in[5];
  const float* c_init = (const float*)d_in[6];
  const float* l2c_W1 = (const float*)d_in[7];
  const float* l2c_b1 = (const float*)d_in[8];
  const float* l2c_W2 = (const float*)d_in[9];
  const float* l2c_b2 = (const float*)d_in[10];
  const float* c2l_W1 = (const float*)d_in[11];
  const float* c2l_b1 = (const float*)d_in[12];
  const float* c2l_W2 = (const float*)d_in[13];
  const float* c2l_b2 = (const float*)d_in[14];
  const float* gc_Wih = (const float*)d_in[15];
  const float* gc_Whh = (const float*)d_in[16];
  const float* gc_bih = (const float*)d_in[17];
  const float* gc_bhh = (const float*)d_in[18];
  const float* gl_Wih = (const float*)d_in[19];
  const float* gl_Whh = (const float*)d_in[20];
  const float* gl_bih = (const float*)d_in[21];
  const float* gl_bhh = (const float*)d_in[22];
  const float* ro_W1 = (const float*)d_in[23];
  const float* ro_b1 = (const float*)d_in[24];
  const float* ro_W2 = (const float*)d_in[25];
  const float* ro_b2 = (const float*)d_in[26];
  const int E = in_sizes[2];
  const int L = in_sizes[4];
  const int C = 100000;

  char* p = (char*)d_ws;
  auto alloc = [&](size_t b) -> char* {
    char* r = p;
    p += (b + 255) & ~(size_t)255;
    return r;
  };
  float* l_emb = (float*)alloc((size_t)L * 64 * 4);
  float* c_emb = (float*)alloc((size_t)C * 64 * 4);
  float* l_msg = (float*)alloc((size_t)L * 64 * 4);
  float* c_msg = (float*)alloc((size_t)C * 64 * 4);
  float* l2c_aggr = (float*)alloc((size_t)C * 64 * 4);
  float* c2l_aggr = (float*)alloc((size_t)L * 64 * 4);
  int* rowptrC = (int*)alloc((size_t)(C + 1) * 4);
  int* rowptrL = (int*)alloc((size_t)(L + 1) * 4);
  int* curC = (int*)alloc((size_t)C * 4);
  int* curL = (int*)alloc((size_t)L * 4);
  int* srcL2C = (int*)alloc((size_t)E * 4);
  int* srcC2L = (int*)alloc((size_t)E * 4);
  int* bsum = (int*)alloc(256 * 4);
  float* gsum = (float*)alloc(128 * 64 * 4);
  float* gcnt = (float*)alloc(128 * 4);
  unsigned short* gGl = (unsigned short*)alloc(73728 * 2);
  unsigned short* gGc = (unsigned short*)alloc(49152 * 2);
  unsigned short* gMl = (unsigned short*)alloc(16384 * 2);
  unsigned short* gMc = (unsigned short*)alloc(16384 * 2);

  // weight prep (once per launch)
  prep_split<<<8, 256, 0, stream>>>(gl_Wih, gl_Whh, gc_Wih, gc_Whh,
                                    l2c_W1, l2c_W2, c2l_W1, c2l_W2,
                                    gGl, gGc, gMl, gMc);

  // CSR build (once per launch; reused by all 16 aggregations)
  hipMemsetAsync(curC, 0, (size_t)C * 4, stream);
  hipMemsetAsync(curL, 0, (size_t)L * 4, stream);
  count_kernel<<<512, 256, 0, stream>>>(le, ce, curL, curC, E);
  int chC = (C + 255) / 256, chL = (L + 255) / 256;
  scan_pass1<<<256, 256, 0, stream>>>(curC, bsum, C, chC);
  scan_pass2<<<1, 256, 0, stream>>>(bsum, rowptrC + C);
  scan_pass3<<<256, 256, 0, stream>>>(curC, bsum, rowptrC, C, chC);
  scan_pass1<<<256, 256, 0, stream>>>(curL, bsum, L, chL);
  scan_pass2<<<1, 256, 0, stream>>>(bsum, rowptrL + L);
  scan_pass3<<<256, 256, 0, stream>>>(curL, bsum, rowptrL, L, chL);
  hipMemcpyAsync(curC, rowptrC, (size_t)C * 4, hipMemcpyDeviceToDevice, stream);
  hipMemcpyAsync(curL, rowptrL, (size_t)L * 4, hipMemcpyDeviceToDevice, stream);
  fill_kernel<<<512, 256, 0, stream>>>(le, ce, curL, curC, srcL2C, srcC2L, E);

  init_emb<<<1024, 256, 0, stream>>>(l_emb, l_init, L * 64);
  init_emb<<<1024, 256, 0, stream>>>(c_emb, c_init, C * 64);

  int TL = L >> 4, TC = C >> 4;
  for (int it = 0; it < 8; ++it) {
    mlp_kernel<<<768, 256, 0, stream>>>(l_emb, l_msg, TL, gMl, l2c_b1, l2c_b2,
                                        c_emb, c_msg, TC, gMc, c2l_b1, c2l_b2, 512);
    aggr_kernel<<<2048, 256, 0, stream>>>(l_msg, rowptrC, srcL2C, l2c_aggr, C,
                                          c_msg, rowptrL, srcC2L, c2l_aggr, L);
    gru_kernel<64><<<256, 1024, 0, stream>>>(l2c_aggr, c_emb, gGc, gc_bih, gc_bhh, C);
    gru_kernel<128><<<256, 1024, 0, stream>>>(c2l_aggr, l_emb, gGl, gl_bih, gl_bhh, L);
  }

  hipMemsetAsync(gsum, 0, 128 * 64 * 4, stream);
  hipMemsetAsync(gcnt, 0, 128 * 4, stream);
  readout_sum<<<512, 256, 0, stream>>>(l_emb, lb, gsum, gcnt, L);
  final_kernel<<<1, 128, 0, stream>>>(gsum, gcnt, ro_W1, ro_b1, ro_W2, ro_b2,
                                      (float*)d_out);
}

// Round 8
// 6979.406 us; speedup vs baseline: 1.4746x; 1.4746x over previous
//
#include <hip/hip_runtime.h>
#include <stdint.h>

// ---------- types / helpers ----------
typedef short bf16x8 __attribute__((ext_vector_type(8)));   // 8 bf16 = 4 VGPR (MFMA A/B frag)
typedef float f32x4  __attribute__((ext_vector_type(4)));   // MFMA C/D frag

__device__ __forceinline__ unsigned short f2bf(float x) {
  unsigned int u = __builtin_bit_cast(unsigned int, x);
  u += 0x7fffu + ((u >> 16) & 1u);
  return (unsigned short)(u >> 16);
}
__device__ __forceinline__ float bf2f(unsigned short b) {
  unsigned int u = ((unsigned int)b) << 16;
  return __builtin_bit_cast(float, u);
}
__device__ __forceinline__ f32x4 mfma16(bf16x8 a, bf16x8 b, f32x4 c) {
  return __builtin_amdgcn_mfma_f32_16x16x32_bf16(a, b, c, 0, 0, 0);
}
// load 8 consecutive f32, split into hi/lo bf16 (hi+lo ~ f32-exact)
__device__ __forceinline__ void split8(const float* __restrict__ p, bf16x8* h, bf16x8* l) {
  float4 a = *reinterpret_cast<const float4*>(p);
  float4 b = *reinterpret_cast<const float4*>(p + 4);
  float v[8] = {a.x, a.y, a.z, a.w, b.x, b.y, b.z, b.w};
  bf16x8 hh, ll;
#pragma unroll
  for (int i = 0; i < 8; ++i) {
    unsigned short hb = f2bf(v[i]);
    hh[i] = (short)hb;
    ll[i] = (short)f2bf(v[i] - bf2f(hb));
  }
  *h = hh; *l = ll;
}
__device__ __forceinline__ float fexp(float x) {  // e^x via v_exp_f32
  return __builtin_amdgcn_exp2f(x * 1.4426950408889634f);
}
__device__ __forceinline__ float sigm(float x) {
  return __builtin_amdgcn_rcpf(1.f + fexp(-x));
}
__device__ __forceinline__ float tanh_fast(float x) {
  x = fminf(fmaxf(x, -15.f), 15.f);
  float e2 = fexp(2.f * x);
  return (e2 - 1.f) * __builtin_amdgcn_rcpf(e2 + 1.f);
}

// ---------- weight prep: split f32 weights into frag-ordered bf16 hi/lo (once) ----------
// gGl layout (ushort): ihH[0,24576) ihL[24576,49152) hhH[49152,61440) hhL[61440,73728)
// gGc layout:          ihH[0,12288) ihL[12288,24576) hhH[24576,36864) hhL[36864,49152)
// gMl/gMc layout:      W1H[0,4096)  W1L[4096,8192)   W2H[8192,12288)  W2L[12288,16384)
__global__ void prep_split(const float* __restrict__ glWih, const float* __restrict__ glWhh,
                           const float* __restrict__ gcWih, const float* __restrict__ gcWhh,
                           const float* __restrict__ mlW1, const float* __restrict__ mlW2,
                           const float* __restrict__ mcW1, const float* __restrict__ mcW2,
                           unsigned short* __restrict__ gGl, unsigned short* __restrict__ gGc,
                           unsigned short* __restrict__ gMl, unsigned short* __restrict__ gMc) {
  int b = blockIdx.x, t = threadIdx.x;
  const float* src; unsigned short *dh, *dl; int NT, KX;
  switch (b) {
    case 0: src = glWih; dh = gGl;         dl = gGl + 24576; NT = 12; KX = 128; break;
    case 1: src = glWhh; dh = gGl + 49152; dl = gGl + 61440; NT = 12; KX = 64;  break;
    case 2: src = gcWih; dh = gGc;         dl = gGc + 12288; NT = 12; KX = 64;  break;
    case 3: src = gcWhh; dh = gGc + 24576; dl = gGc + 36864; NT = 12; KX = 64;  break;
    case 4: src = mlW1;  dh = gMl;         dl = gMl + 4096;  NT = 4;  KX = 64;  break;
    case 5: src = mlW2;  dh = gMl + 8192;  dl = gMl + 12288; NT = 4;  KX = 64;  break;
    case 6: src = mcW1;  dh = gMc;         dl = gMc + 4096;  NT = 4;  KX = 64;  break;
    default: src = mcW2; dh = gMc + 8192;  dl = gMc + 12288; NT = 4;  KX = 64;  break;
  }
  int NKC = KX / 32;
  int tot = NT * NKC * 64;
  for (int e = t; e < tot; e += 256) {
    int f = e >> 6, l = e & 63;
    int nt = f / NKC, kc = f % NKC;
    int n = nt * 16 + (l & 15), k0 = kc * 32 + (l >> 4) * 8;
    bf16x8 h, lo;
    split8(src + n * KX + k0, &h, &lo);
    *reinterpret_cast<bf16x8*>(dh + e * 8) = h;
    *reinterpret_cast<bf16x8*>(dl + e * 8) = lo;
  }
}

// ---------- fused 2x MLP (grid split), operand-swapped MFMA: D = W·X^T ----------
// lane holds one x-row (lane&15) and 4 consecutive n-cols ((lane>>4)*4+i) -> float4 stores.
__global__ __launch_bounds__(256, 3) void mlp_kernel(
    const float* __restrict__ X1, float* __restrict__ Y1, int T1,
    const unsigned short* __restrict__ g1, const float* __restrict__ B11, const float* __restrict__ B21,
    const float* __restrict__ X2, float* __restrict__ Y2, int T2,
    const unsigned short* __restrict__ g2, const float* __restrict__ B12, const float* __restrict__ B22,
    int G1) {
  const float* X; float* Y; int tiles, b, nb;
  const unsigned short* gw; const float *B1, *B2;
  if ((int)blockIdx.x < G1) {
    X = X1; Y = Y1; tiles = T1; gw = g1; B1 = B11; B2 = B21; b = blockIdx.x; nb = G1;
  } else {
    X = X2; Y = Y2; tiles = T2; gw = g2; B1 = B12; B2 = B22; b = blockIdx.x - G1; nb = gridDim.x - G1;
  }
  __shared__ __align__(16) unsigned short wbuf[16384];
  __shared__ __align__(16) float hbuf[4][16 * 68];
  int tid = threadIdx.x, wid = tid >> 6, lane = tid & 63;
  int r = lane & 15, kb = lane >> 4;
  for (int i4 = tid; i4 < 2048; i4 += 256)
    *reinterpret_cast<int4*>(wbuf + i4 * 8) = *reinterpret_cast<const int4*>(gw + i4 * 8);
  __syncthreads();
  const unsigned short *w1h = wbuf, *w1l = wbuf + 4096, *w2h = wbuf + 8192, *w2l = wbuf + 12288;
  f32x4 b1f[4], b2f[4];
#pragma unroll
  for (int nt = 0; nt < 4; ++nt) {
    b1f[nt] = *reinterpret_cast<const f32x4*>(B1 + nt * 16 + kb * 4);
    b2f[nt] = *reinterpret_cast<const f32x4*>(B2 + nt * 16 + kb * 4);
  }
  float* hl = hbuf[wid];
  for (int t = b * 4 + wid; t < tiles; t += nb * 4) {
    int row0 = t << 4;
    const float* xp = X + (size_t)(row0 + r) * 64 + kb * 8;
    bf16x8 a0h, a0l, a1h, a1l;
    split8(xp, &a0h, &a0l);
    split8(xp + 32, &a1h, &a1l);
#pragma unroll
    for (int nt = 0; nt < 4; ++nt) {
      f32x4 c = b1f[nt];
      bf16x8 wh = *reinterpret_cast<const bf16x8*>(w1h + ((nt * 2 + 0) * 64 + lane) * 8);
      bf16x8 wl = *reinterpret_cast<const bf16x8*>(w1l + ((nt * 2 + 0) * 64 + lane) * 8);
      c = mfma16(wh, a0l, c); c = mfma16(wl, a0h, c); c = mfma16(wh, a0h, c);
      wh = *reinterpret_cast<const bf16x8*>(w1h + ((nt * 2 + 1) * 64 + lane) * 8);
      wl = *reinterpret_cast<const bf16x8*>(w1l + ((nt * 2 + 1) * 64 + lane) * 8);
      c = mfma16(wh, a1l, c); c = mfma16(wl, a1h, c); c = mfma16(wh, a1h, c);
#pragma unroll
      for (int i = 0; i < 4; ++i) c[i] = fmaxf(c[i], 0.f);
      *reinterpret_cast<f32x4*>(hl + r * 68 + nt * 16 + kb * 4) = c;  // b128 write, own row
    }
    // same-wave LDS RAW: DS pipe is in-order within a wave
    bf16x8 h0h, h0l, h1h, h1l;
    split8(hl + r * 68 + kb * 8, &h0h, &h0l);
    split8(hl + r * 68 + 32 + kb * 8, &h1h, &h1l);
    float* yp = Y + (size_t)row0 * 64;
#pragma unroll
    for (int nt = 0; nt < 4; ++nt) {
      f32x4 c = b2f[nt];
      bf16x8 wh = *reinterpret_cast<const bf16x8*>(w2h + ((nt * 2 + 0) * 64 + lane) * 8);
      bf16x8 wl = *reinterpret_cast<const bf16x8*>(w2l + ((nt * 2 + 0) * 64 + lane) * 8);
      c = mfma16(wh, h0l, c); c = mfma16(wl, h0h, c); c = mfma16(wh, h0h, c);
      wh = *reinterpret_cast<const bf16x8*>(w2h + ((nt * 2 + 1) * 64 + lane) * 8);
      wl = *reinterpret_cast<const bf16x8*>(w2l + ((nt * 2 + 1) * 64 + lane) * 8);
      c = mfma16(wh, h1l, c); c = mfma16(wl, h1h, c); c = mfma16(wh, h1h, c);
      *reinterpret_cast<f32x4*>(yp + (size_t)r * 64 + nt * 16 + kb * 4) = c;  // float4 store
    }
  }
}

// ---------- GRU cell, in place, hi/lo 3-term, swapped MFMA, LDS weights ----------
// 512 threads, min-1-wave bound: up to 256 VGPR -> whole live set resident, ZERO spill.
template <int KX>
__global__ __launch_bounds__(512, 1) void gru_kernel(
    const float* __restrict__ Xa, float* __restrict__ H,
    const unsigned short* __restrict__ gws,
    const float* __restrict__ Bih, const float* __restrict__ Bhh, int M) {
  constexpr int NKC_X = KX / 32;
  constexpr int NFX = 12 * NKC_X;
  constexpr int IHL = NFX * 512;       // ihL offset (ushorts)
  constexpr int HH0 = 2 * NFX * 512;   // hhH
  constexpr int HHL = HH0 + 12288;     // hhL
  constexpr int TOTU = HH0 + 24576;
  __shared__ __align__(16) unsigned short wlds[TOTU];
  __shared__ __align__(16) float ldsB[256];  // [0,64) r-sum [64,128) z-sum [128,192) bnI [192,256) bnH
  int tid = threadIdx.x;
  for (int i4 = tid; i4 < TOTU / 8; i4 += 512)
    *reinterpret_cast<int4*>(wlds + i4 * 8) = *reinterpret_cast<const int4*>(gws + i4 * 8);
  if (tid < 128) ldsB[tid] = Bih[tid] + Bhh[tid];
  else if (tid < 192) ldsB[tid] = Bih[tid];            // bnI: Bih[128+j] at ldsB[128+j]
  else if (tid < 256) ldsB[tid] = Bhh[tid - 64];       // bnH: Bhh[128+j] at ldsB[192+j]
  __syncthreads();
  int wid = tid >> 6, lane = tid & 63;
  int r = lane & 15, kb = lane >> 4;
  int tiles = M >> 4;
  for (int t = blockIdx.x * 8 + wid; t < tiles; t += gridDim.x * 8) {
    int row0 = t << 4;
    bf16x8 axh[NKC_X], axl[NKC_X], ahh[2], ahl[2];
#pragma unroll
    for (int kc = 0; kc < 2; ++kc)
      split8(Xa + (size_t)(row0 + r) * 64 + kc * 32 + kb * 8, &axh[kc], &axl[kc]);
    if (KX == 128) {
#pragma unroll
      for (int kc = 0; kc < 2; ++kc)  // pair-flip lives inside this 16-row tile
        split8(H + (size_t)((row0 + r) ^ 1) * 64 + kc * 32 + kb * 8, &axh[2 + kc], &axl[2 + kc]);
    }
#pragma unroll
    for (int kc = 0; kc < 2; ++kc)
      split8(H + (size_t)(row0 + r) * 64 + kc * 32 + kb * 8, &ahh[kc], &ahl[kc]);

    auto dot_ih = [&](int nt) -> f32x4 {
      f32x4 c; c[0] = c[1] = c[2] = c[3] = 0.f;
#pragma unroll
      for (int kc = 0; kc < NKC_X; ++kc) {
        bf16x8 wh = *reinterpret_cast<const bf16x8*>(wlds + (nt * NKC_X + kc) * 512 + lane * 8);
        bf16x8 wl = *reinterpret_cast<const bf16x8*>(wlds + IHL + (nt * NKC_X + kc) * 512 + lane * 8);
        c = mfma16(wh, axl[kc], c);
        c = mfma16(wl, axh[kc], c);
        c = mfma16(wh, axh[kc], c);
      }
      return c;
    };
    auto dot_hh = [&](int nt) -> f32x4 {
      f32x4 c; c[0] = c[1] = c[2] = c[3] = 0.f;
#pragma unroll
      for (int kc = 0; kc < 2; ++kc) {
        bf16x8 wh = *reinterpret_cast<const bf16x8*>(wlds + HH0 + (nt * 2 + kc) * 512 + lane * 8);
        bf16x8 wl = *reinterpret_cast<const bf16x8*>(wlds + HHL + (nt * 2 + kc) * 512 + lane * 8);
        c = mfma16(wh, ahl[kc], c);
        c = mfma16(wl, ahh[kc], c);
        c = mfma16(wh, ahh[kc], c);
      }
      return c;
    };

#pragma unroll
    for (int q = 0; q < 4; ++q) {
      f32x4 pr = dot_ih(q);     f32x4 qr = dot_hh(q);
      f32x4 pz = dot_ih(q + 4); f32x4 qz = dot_hh(q + 4);
      f32x4 pn = dot_ih(q + 8); f32x4 qn = dot_hh(q + 8);
      int cb = q * 16 + kb * 4;  // 4 consecutive H columns owned by this lane
      f32x4 bR = *reinterpret_cast<const f32x4*>(ldsB + cb);
      f32x4 bZ = *reinterpret_cast<const f32x4*>(ldsB + 64 + cb);
      f32x4 bI = *reinterpret_cast<const f32x4*>(ldsB + 128 + cb);
      f32x4 bH = *reinterpret_cast<const f32x4*>(ldsB + 192 + cb);
      float* hp = H + (size_t)(row0 + r) * 64 + cb;
      f32x4 hv = *reinterpret_cast<const f32x4*>(hp);
      f32x4 hn;
#pragma unroll
      for (int i = 0; i < 4; ++i) {
        float rg = sigm(pr[i] + qr[i] + bR[i]);
        float zg = sigm(pz[i] + qz[i] + bZ[i]);
        float tn = tanh_fast(pn[i] + bI[i] + rg * (qn[i] + bH[i]));
        hn[i] = (1.f - zg) * tn + zg * hv[i];
      }
      *reinterpret_cast<f32x4*>(hp) = hn;  // aligned float4 store
    }
  }
}

// ---------- fused 2x CSR gather aggregation (grid split over dst ranges) ----------
__global__ __launch_bounds__(256, 6) void aggr_kernel(
    const float* __restrict__ msgA, const int* __restrict__ rpA,
    const int* __restrict__ srcA, float* __restrict__ outA, int NA,
    const float* __restrict__ msgB, const int* __restrict__ rpB,
    const int* __restrict__ srcB, float* __restrict__ outB, int NB) {
  int gtid = blockIdx.x * 256 + threadIdx.x;
  int w = gtid >> 6, lane = gtid & 63;
  int nw = gridDim.x * 4;
  int tot = NA + NB;
  for (int d = w; d < tot; d += nw) {
    const float* msg; const int* rp; const int* srcv; float* out; int dst;
    if (d < NA) { msg = msgA; rp = rpA; srcv = srcA; out = outA; dst = d; }
    else        { msg = msgB; rp = rpB; srcv = srcB; out = outB; dst = d - NA; }
    int p0 = rp[dst], p1 = rp[dst + 1];
    float acc = 0.f;
    int j = p0;
    for (; j + 8 <= p1; j += 8) {
      int s0 = srcv[j],     s1 = srcv[j + 1], s2 = srcv[j + 2], s3 = srcv[j + 3];
      int s4 = srcv[j + 4], s5 = srcv[j + 5], s6 = srcv[j + 6], s7 = srcv[j + 7];
      float a0 = msg[(size_t)s0 * 64 + lane];
      float a1 = msg[(size_t)s1 * 64 + lane];
      float a2 = msg[(size_t)s2 * 64 + lane];
      float a3 = msg[(size_t)s3 * 64 + lane];
      float a4 = msg[(size_t)s4 * 64 + lane];
      float a5 = msg[(size_t)s5 * 64 + lane];
      float a6 = msg[(size_t)s6 * 64 + lane];
      float a7 = msg[(size_t)s7 * 64 + lane];
      acc += a0; acc += a1; acc += a2; acc += a3;
      acc += a4; acc += a5; acc += a6; acc += a7;
    }
    for (; j < p1; ++j) acc += msg[(size_t)srcv[j] * 64 + lane];
    out[(size_t)dst * 64 + lane] = acc;
  }
}

// ---------- CSR build ----------
__global__ void count_kernel(const int* __restrict__ le, const int* __restrict__ ce,
                             int* __restrict__ degL, int* __restrict__ degC, int E) {
  for (int e = blockIdx.x * 256 + threadIdx.x; e < E; e += gridDim.x * 256) {
    atomicAdd(&degL[le[e]], 1);
    atomicAdd(&degC[ce[e]], 1);
  }
}
__global__ void scan_pass1(const int* __restrict__ in, int* __restrict__ bsum, int N, int chunk) {
  int b = blockIdx.x, t = threadIdx.x;
  int base = b * chunk;
  int seg = (chunk + 255) >> 8;
  int a = base + t * seg;
  int e = min(min(N, base + chunk), a + seg);
  int s = 0;
  for (int i = a; i < e; ++i) s += in[i];
  __shared__ int red[256];
  red[t] = s; __syncthreads();
  for (int off = 128; off > 0; off >>= 1) {
    if (t < off) red[t] += red[t + off];
    __syncthreads();
  }
  if (t == 0) bsum[b] = red[0];
}
__global__ void scan_pass2(int* bsum, int* totalOut) {
  __shared__ int sc[256];
  int t = threadIdx.x;
  int v = bsum[t];
  sc[t] = v; __syncthreads();
  for (int off = 1; off < 256; off <<= 1) {
    int u = (t >= off) ? sc[t - off] : 0;
    __syncthreads();
    sc[t] += u;
    __syncthreads();
  }
  bsum[t] = sc[t] - v;
  if (t == 255) *totalOut = sc[255];
}
__global__ void scan_pass3(const int* __restrict__ in, const int* __restrict__ bsum,
                           int* __restrict__ outp, int N, int chunk) {
  int b = blockIdx.x, t = threadIdx.x;
  int base = b * chunk;
  int seg = (chunk + 255) >> 8;
  int a = base + t * seg;
  int e = min(min(N, base + chunk), a + seg);
  int s = 0;
  for (int i = a; i < e; ++i) s += in[i];
  __shared__ int sc[256];
  int v = s;
  sc[t] = v; __syncthreads();
  for (int off = 1; off < 256; off <<= 1) {
    int u = (t >= off) ? sc[t - off] : 0;
    __syncthreads();
    sc[t] += u;
    __syncthreads();
  }
  int run = bsum[b] + sc[t] - v;
  for (int i = a; i < e; ++i) { outp[i] = run; run += in[i]; }
}
__global__ void fill_kernel(const int* __restrict__ le, const int* __restrict__ ce,
                            int* __restrict__ curL, int* __restrict__ curC,
                            int* __restrict__ srcL2C, int* __restrict__ srcC2L, int E) {
  for (int e = blockIdx.x * 256 + threadIdx.x; e < E; e += gridDim.x * 256) {
    int ls = le[e], cd = ce[e];
    int s1 = atomicAdd(&curC[cd], 1);
    srcL2C[s1] = ls;
    int s2 = atomicAdd(&curL[ls], 1);
    srcC2L[s2] = cd;
  }
}

// ---------- init / readout ----------
__global__ void init_emb(float* __restrict__ emb, const float* __restrict__ ini, int n) {
  for (int i = blockIdx.x * 256 + threadIdx.x; i < n; i += gridDim.x * 256)
    emb[i] = ini[i & 63];
}
__global__ void readout_sum(const float* __restrict__ lemb, const int* __restrict__ lb,
                            float* __restrict__ gsum, float* __restrict__ gcnt, int L) {
  int gtid = blockIdx.x * 256 + threadIdx.x;
  int w = gtid >> 6, lane = gtid & 63;
  int nw = gridDim.x * 4;
  int chunk = (L + nw - 1) / nw;
  int s = w * chunk, e = min(L, s + chunk);
  if (s >= e) return;
  float acc = 0.f, cnt = 0.f;
  int curb = lb[s];
  for (int row = s; row < e; ++row) {
    int b = lb[row];
    if (b != curb) {
      atomicAdd(&gsum[curb * 64 + lane], acc);
      if (lane == 0) atomicAdd(&gcnt[curb], cnt);
      acc = 0.f; cnt = 0.f; curb = b;
    }
    acc += lemb[(size_t)row * 64 + lane];
    cnt += 1.f;
  }
  atomicAdd(&gsum[curb * 64 + lane], acc);
  if (lane == 0) atomicAdd(&gcnt[curb], cnt);
}
__global__ void final_kernel(const float* __restrict__ gsum, const float* __restrict__ gcnt,
                             const float* __restrict__ W1, const float* __restrict__ B1,
                             const float* __restrict__ W2, const float* __restrict__ B2,
                             float* __restrict__ outp) {
  __shared__ float w1s[4096];
  __shared__ float w2s[64];
  int t = threadIdx.x;  // 128 threads: one per graph
  for (int i = t; i < 4096; i += 128) w1s[i] = W1[i];
  if (t < 64) w2s[t] = W2[t];
  __syncthreads();
  float x[64];
  float c = fmaxf(gcnt[t], 1.f);
#pragma unroll
  for (int d = 0; d < 64; ++d) x[d] = gsum[t * 64 + d] / c;
  float acc = B2[0];
  for (int j = 0; j < 64; ++j) {
    float h = B1[j];
#pragma unroll
    for (int k = 0; k < 64; ++k) h += x[k] * w1s[j * 64 + k];
    acc += fmaxf(h, 0.f) * w2s[j];
  }
  outp[t] = 1.f / (1.f + __expf(-acc));
}

// ---------- launch ----------
extern "C" void kernel_launch(void* const* d_in, const int* in_sizes, int n_in,
                              void* d_out, int out_size, void* d_ws, size_t ws_size,
                              hipStream_t stream) {
  const int* le = (const int*)d_in[2];
  const int* ce = (const int*)d_in[3];
  const int* lb = (const int*)d_in[4];
  const float* l_init = (const float*)d_in[5];
  const float* c_init = (const float*)d_in[6];
  const float* l2c_W1 = (const float*)d_in[7];
  const float* l2c_b1 = (const float*)d_in[8];
  const float* l2c_W2 = (const float*)d_in[9];
  const float* l2c_b2 = (const float*)d_in[10];
  const float* c2l_W1 = (const float*)d_in[11];
  const float* c2l_b1 = (const float*)d_in[12];
  const float* c2l_W2 = (const float*)d_in[13];
  const float* c2l_b2 = (const float*)d_in[14];
  const float* gc_Wih = (const float*)d_in[15];
  const float* gc_Whh = (const float*)d_in[16];
  const float* gc_bih = (const float*)d_in[17];
  const float* gc_bhh = (const float*)d_in[18];
  const float* gl_Wih = (const float*)d_in[19];
  const float* gl_Whh = (const float*)d_in[20];
  const float* gl_bih = (const float*)d_in[21];
  const float* gl_bhh = (const float*)d_in[22];
  const float* ro_W1 = (const float*)d_in[23];
  const float* ro_b1 = (const float*)d_in[24];
  const float* ro_W2 = (const float*)d_in[25];
  const float* ro_b2 = (const float*)d_in[26];
  const int E = in_sizes[2];
  const int L = in_sizes[4];
  const int C = 100000;

  char* p = (char*)d_ws;
  auto alloc = [&](size_t b) -> char* {
    char* r = p;
    p += (b + 255) & ~(size_t)255;
    return r;
  };
  float* l_emb = (float*)alloc((size_t)L * 64 * 4);
  float* c_emb = (float*)alloc((size_t)C * 64 * 4);
  float* l_msg = (float*)alloc((size_t)L * 64 * 4);
  float* c_msg = (float*)alloc((size_t)C * 64 * 4);
  float* l2c_aggr = (float*)alloc((size_t)C * 64 * 4);
  float* c2l_aggr = (float*)alloc((size_t)L * 64 * 4);
  int* rowptrC = (int*)alloc((size_t)(C + 1) * 4);
  int* rowptrL = (int*)alloc((size_t)(L + 1) * 4);
  int* curC = (int*)alloc((size_t)C * 4);
  int* curL = (int*)alloc((size_t)L * 4);
  int* srcL2C = (int*)alloc((size_t)E * 4);
  int* srcC2L = (int*)alloc((size_t)E * 4);
  int* bsum = (int*)alloc(256 * 4);
  float* gsum = (float*)alloc(128 * 64 * 4);
  float* gcnt = (float*)alloc(128 * 4);
  unsigned short* gGl = (unsigned short*)alloc(73728 * 2);
  unsigned short* gGc = (unsigned short*)alloc(49152 * 2);
  unsigned short* gMl = (unsigned short*)alloc(16384 * 2);
  unsigned short* gMc = (unsigned short*)alloc(16384 * 2);

  // weight prep (once per launch)
  prep_split<<<8, 256, 0, stream>>>(gl_Wih, gl_Whh, gc_Wih, gc_Whh,
                                    l2c_W1, l2c_W2, c2l_W1, c2l_W2,
                                    gGl, gGc, gMl, gMc);

  // CSR build (once per launch; reused by all 16 aggregations)
  hipMemsetAsync(curC, 0, (size_t)C * 4, stream);
  hipMemsetAsync(curL, 0, (size_t)L * 4, stream);
  count_kernel<<<512, 256, 0, stream>>>(le, ce, curL, curC, E);
  int chC = (C + 255) / 256, chL = (L + 255) / 256;
  scan_pass1<<<256, 256, 0, stream>>>(curC, bsum, C, chC);
  scan_pass2<<<1, 256, 0, stream>>>(bsum, rowptrC + C);
  scan_pass3<<<256, 256, 0, stream>>>(curC, bsum, rowptrC, C, chC);
  scan_pass1<<<256, 256, 0, stream>>>(curL, bsum, L, chL);
  scan_pass2<<<1, 256, 0, stream>>>(bsum, rowptrL + L);
  scan_pass3<<<256, 256, 0, stream>>>(curL, bsum, rowptrL, L, chL);
  hipMemcpyAsync(curC, rowptrC, (size_t)C * 4, hipMemcpyDeviceToDevice, stream);
  hipMemcpyAsync(curL, rowptrL, (size_t)L * 4, hipMemcpyDeviceToDevice, stream);
  fill_kernel<<<512, 256, 0, stream>>>(le, ce, curL, curC, srcL2C, srcC2L, E);

  init_emb<<<1024, 256, 0, stream>>>(l_emb, l_init, L * 64);
  init_emb<<<1024, 256, 0, stream>>>(c_emb, c_init, C * 64);

  int TL = L >> 4, TC = C >> 4;
  for (int it = 0; it < 8; ++it) {
    mlp_kernel<<<768, 256, 0, stream>>>(l_emb, l_msg, TL, gMl, l2c_b1, l2c_b2,
                                        c_emb, c_msg, TC, gMc, c2l_b1, c2l_b2, 512);
    aggr_kernel<<<2048, 256, 0, stream>>>(l_msg, rowptrC, srcL2C, l2c_aggr, C,
                                          c_msg, rowptrL, srcC2L, c2l_aggr, L);
    gru_kernel<64><<<256, 512, 0, stream>>>(l2c_aggr, c_emb, gGc, gc_bih, gc_bhh, C);
    gru_kernel<128><<<256, 512, 0, stream>>>(c2l_aggr, l_emb, gGl, gl_bih, gl_bhh, L);
  }

  hipMemsetAsync(gsum, 0, 128 * 64 * 4, stream);
  hipMemsetAsync(gcnt, 0, 128 * 4, stream);
  readout_sum<<<512, 256, 0, stream>>>(l_emb, lb, gsum, gcnt, L);
  final_kernel<<<1, 128, 0, stream>>>(gsum, gcnt, ro_W1, ro_b1, ro_W2, ro_b2,
                                      (float*)d_out);
}

// Round 9
// 3064.225 us; speedup vs baseline: 3.3588x; 2.2777x over previous
//
#include <hip/hip_runtime.h>
#include <stdint.h>

// ---------- types / helpers ----------
typedef short bf16x8 __attribute__((ext_vector_type(8)));   // 8 bf16 = 4 VGPR (MFMA A/B frag)
typedef float f32x4  __attribute__((ext_vector_type(4)));   // MFMA C/D frag

__device__ __forceinline__ unsigned short f2bf(float x) {
  unsigned int u = __builtin_bit_cast(unsigned int, x);
  u += 0x7fffu + ((u >> 16) & 1u);
  return (unsigned short)(u >> 16);
}
__device__ __forceinline__ float bf2f(unsigned short b) {
  unsigned int u = ((unsigned int)b) << 16;
  return __builtin_bit_cast(float, u);
}
__device__ __forceinline__ f32x4 mfma16(bf16x8 a, bf16x8 b, f32x4 c) {
  return __builtin_amdgcn_mfma_f32_16x16x32_bf16(a, b, c, 0, 0, 0);
}
// load 8 consecutive f32, split into hi/lo bf16 (hi+lo ~ f32-exact)
__device__ __forceinline__ void split8(const float* __restrict__ p, bf16x8* h, bf16x8* l) {
  float4 a = *reinterpret_cast<const float4*>(p);
  float4 b = *reinterpret_cast<const float4*>(p + 4);
  float v[8] = {a.x, a.y, a.z, a.w, b.x, b.y, b.z, b.w};
  bf16x8 hh, ll;
#pragma unroll
  for (int i = 0; i < 8; ++i) {
    unsigned short hb = f2bf(v[i]);
    hh[i] = (short)hb;
    ll[i] = (short)f2bf(v[i] - bf2f(hb));
  }
  *h = hh; *l = ll;
}
__device__ __forceinline__ float fexp(float x) {  // e^x via v_exp_f32
  return __builtin_amdgcn_exp2f(x * 1.4426950408889634f);
}
__device__ __forceinline__ float sigm(float x) {
  return __builtin_amdgcn_rcpf(1.f + fexp(-x));
}
__device__ __forceinline__ float tanh_fast(float x) {
  x = fminf(fmaxf(x, -15.f), 15.f);
  float e2 = fexp(2.f * x);
  return (e2 - 1.f) * __builtin_amdgcn_rcpf(e2 + 1.f);
}

// ---------- weight prep: split f32 weights into frag-ordered bf16 hi/lo (once) ----------
// gGl layout (ushort): ihH[0,24576) ihL[24576,49152) hhH[49152,61440) hhL[61440,73728)
// gGc layout:          ihH[0,12288) ihL[12288,24576) hhH[24576,36864) hhL[36864,49152)
// gMl/gMc layout:      W1H[0,4096)  W1L[4096,8192)   W2H[8192,12288)  W2L[12288,16384)
__global__ void prep_split(const float* __restrict__ glWih, const float* __restrict__ glWhh,
                           const float* __restrict__ gcWih, const float* __restrict__ gcWhh,
                           const float* __restrict__ mlW1, const float* __restrict__ mlW2,
                           const float* __restrict__ mcW1, const float* __restrict__ mcW2,
                           unsigned short* __restrict__ gGl, unsigned short* __restrict__ gGc,
                           unsigned short* __restrict__ gMl, unsigned short* __restrict__ gMc) {
  int b = blockIdx.x, t = threadIdx.x;
  const float* src; unsigned short *dh, *dl; int NT, KX;
  switch (b) {
    case 0: src = glWih; dh = gGl;         dl = gGl + 24576; NT = 12; KX = 128; break;
    case 1: src = glWhh; dh = gGl + 49152; dl = gGl + 61440; NT = 12; KX = 64;  break;
    case 2: src = gcWih; dh = gGc;         dl = gGc + 12288; NT = 12; KX = 64;  break;
    case 3: src = gcWhh; dh = gGc + 24576; dl = gGc + 36864; NT = 12; KX = 64;  break;
    case 4: src = mlW1;  dh = gMl;         dl = gMl + 4096;  NT = 4;  KX = 64;  break;
    case 5: src = mlW2;  dh = gMl + 8192;  dl = gMl + 12288; NT = 4;  KX = 64;  break;
    case 6: src = mcW1;  dh = gMc;         dl = gMc + 4096;  NT = 4;  KX = 64;  break;
    default: src = mcW2; dh = gMc + 8192;  dl = gMc + 12288; NT = 4;  KX = 64;  break;
  }
  int NKC = KX / 32;
  int tot = NT * NKC * 64;
  for (int e = t; e < tot; e += 256) {
    int f = e >> 6, l = e & 63;
    int nt = f / NKC, kc = f % NKC;
    int n = nt * 16 + (l & 15), k0 = kc * 32 + (l >> 4) * 8;
    bf16x8 h, lo;
    split8(src + n * KX + k0, &h, &lo);
    *reinterpret_cast<bf16x8*>(dh + e * 8) = h;
    *reinterpret_cast<bf16x8*>(dl + e * 8) = lo;
  }
}

// ---------- fused 2x MLP (grid split), operand-swapped MFMA: D = W·X^T ----------
// lane holds one x-row (lane&15) and 4 consecutive n-cols ((lane>>4)*4+i) -> float4 stores.
__global__ __launch_bounds__(256, 3) void mlp_kernel(
    const float* __restrict__ X1, float* __restrict__ Y1, int T1,
    const unsigned short* __restrict__ g1, const float* __restrict__ B11, const float* __restrict__ B21,
    const float* __restrict__ X2, float* __restrict__ Y2, int T2,
    const unsigned short* __restrict__ g2, const float* __restrict__ B12, const float* __restrict__ B22,
    int G1) {
  const float* X; float* Y; int tiles, b, nb;
  const unsigned short* gw; const float *B1, *B2;
  if ((int)blockIdx.x < G1) {
    X = X1; Y = Y1; tiles = T1; gw = g1; B1 = B11; B2 = B21; b = blockIdx.x; nb = G1;
  } else {
    X = X2; Y = Y2; tiles = T2; gw = g2; B1 = B12; B2 = B22; b = blockIdx.x - G1; nb = gridDim.x - G1;
  }
  __shared__ __align__(16) unsigned short wbuf[16384];
  __shared__ __align__(16) float hbuf[4][16 * 68];
  int tid = threadIdx.x, wid = tid >> 6, lane = tid & 63;
  int r = lane & 15, kb = lane >> 4;
  for (int i4 = tid; i4 < 2048; i4 += 256)
    *reinterpret_cast<int4*>(wbuf + i4 * 8) = *reinterpret_cast<const int4*>(gw + i4 * 8);
  __syncthreads();
  const unsigned short *w1h = wbuf, *w1l = wbuf + 4096, *w2h = wbuf + 8192, *w2l = wbuf + 12288;
  f32x4 b1f[4], b2f[4];
#pragma unroll
  for (int nt = 0; nt < 4; ++nt) {
    b1f[nt] = *reinterpret_cast<const f32x4*>(B1 + nt * 16 + kb * 4);
    b2f[nt] = *reinterpret_cast<const f32x4*>(B2 + nt * 16 + kb * 4);
  }
  float* hl = hbuf[wid];
  for (int t = b * 4 + wid; t < tiles; t += nb * 4) {
    int row0 = t << 4;
    const float* xp = X + (size_t)(row0 + r) * 64 + kb * 8;
    bf16x8 a0h, a0l, a1h, a1l;
    split8(xp, &a0h, &a0l);
    split8(xp + 32, &a1h, &a1l);
#pragma unroll
    for (int nt = 0; nt < 4; ++nt) {
      f32x4 c = b1f[nt];
      bf16x8 wh = *reinterpret_cast<const bf16x8*>(w1h + ((nt * 2 + 0) * 64 + lane) * 8);
      bf16x8 wl = *reinterpret_cast<const bf16x8*>(w1l + ((nt * 2 + 0) * 64 + lane) * 8);
      c = mfma16(wh, a0l, c); c = mfma16(wl, a0h, c); c = mfma16(wh, a0h, c);
      wh = *reinterpret_cast<const bf16x8*>(w1h + ((nt * 2 + 1) * 64 + lane) * 8);
      wl = *reinterpret_cast<const bf16x8*>(w1l + ((nt * 2 + 1) * 64 + lane) * 8);
      c = mfma16(wh, a1l, c); c = mfma16(wl, a1h, c); c = mfma16(wh, a1h, c);
#pragma unroll
      for (int i = 0; i < 4; ++i) c[i] = fmaxf(c[i], 0.f);
      *reinterpret_cast<f32x4*>(hl + r * 68 + nt * 16 + kb * 4) = c;  // b128 write, own row
    }
    // same-wave LDS RAW: DS pipe is in-order within a wave
    bf16x8 h0h, h0l, h1h, h1l;
    split8(hl + r * 68 + kb * 8, &h0h, &h0l);
    split8(hl + r * 68 + 32 + kb * 8, &h1h, &h1l);
    float* yp = Y + (size_t)row0 * 64;
#pragma unroll
    for (int nt = 0; nt < 4; ++nt) {
      f32x4 c = b2f[nt];
      bf16x8 wh = *reinterpret_cast<const bf16x8*>(w2h + ((nt * 2 + 0) * 64 + lane) * 8);
      bf16x8 wl = *reinterpret_cast<const bf16x8*>(w2l + ((nt * 2 + 0) * 64 + lane) * 8);
      c = mfma16(wh, h0l, c); c = mfma16(wl, h0h, c); c = mfma16(wh, h0h, c);
      wh = *reinterpret_cast<const bf16x8*>(w2h + ((nt * 2 + 1) * 64 + lane) * 8);
      wl = *reinterpret_cast<const bf16x8*>(w2l + ((nt * 2 + 1) * 64 + lane) * 8);
      c = mfma16(wh, h1l, c); c = mfma16(wl, h1h, c); c = mfma16(wh, h1h, c);
      *reinterpret_cast<f32x4*>(yp + (size_t)r * 64 + nt * 16 + kb * 4) = c;  // float4 store
    }
  }
}

// ---------- GRU cell, in place, hi/lo 3-term, swapped MFMA, LDS weights ----------
// 512 threads, min-1-wave bound. q loop NOT unrolled: keeps live set + scheduler
// temporaries inside 128 VGPR (fully unrolled version spilled ~250 MB/dispatch).
template <int KX>
__global__ __launch_bounds__(512, 1) void gru_kernel(
    const float* __restrict__ Xa, float* __restrict__ H,
    const unsigned short* __restrict__ gws,
    const float* __restrict__ Bih, const float* __restrict__ Bhh, int M) {
  constexpr int NKC_X = KX / 32;
  constexpr int NFX = 12 * NKC_X;
  constexpr int IHL = NFX * 512;       // ihL offset (ushorts)
  constexpr int HH0 = 2 * NFX * 512;   // hhH
  constexpr int HHL = HH0 + 12288;     // hhL
  constexpr int TOTU = HH0 + 24576;
  __shared__ __align__(16) unsigned short wlds[TOTU];
  __shared__ __align__(16) float ldsB[256];  // [0,64) r-sum [64,128) z-sum [128,192) bnI [192,256) bnH
  int tid = threadIdx.x;
  for (int i4 = tid; i4 < TOTU / 8; i4 += 512)
    *reinterpret_cast<int4*>(wlds + i4 * 8) = *reinterpret_cast<const int4*>(gws + i4 * 8);
  if (tid < 128) ldsB[tid] = Bih[tid] + Bhh[tid];
  else if (tid < 192) ldsB[tid] = Bih[tid];            // bnI: Bih[128+j] at ldsB[128+j]
  else if (tid < 256) ldsB[tid] = Bhh[tid - 64];       // bnH: Bhh[128+j] at ldsB[192+j]
  __syncthreads();
  int wid = tid >> 6, lane = tid & 63;
  int r = lane & 15, kb = lane >> 4;
  int tiles = M >> 4;
  for (int t = blockIdx.x * 8 + wid; t < tiles; t += gridDim.x * 8) {
    int row0 = t << 4;
    bf16x8 axh[NKC_X], axl[NKC_X], ahh[2], ahl[2];
#pragma unroll
    for (int kc = 0; kc < 2; ++kc)
      split8(Xa + (size_t)(row0 + r) * 64 + kc * 32 + kb * 8, &axh[kc], &axl[kc]);
    if (KX == 128) {
#pragma unroll
      for (int kc = 0; kc < 2; ++kc)  // pair-flip lives inside this 16-row tile
        split8(H + (size_t)((row0 + r) ^ 1) * 64 + kc * 32 + kb * 8, &axh[2 + kc], &axl[2 + kc]);
    }
#pragma unroll
    for (int kc = 0; kc < 2; ++kc)
      split8(H + (size_t)(row0 + r) * 64 + kc * 32 + kb * 8, &ahh[kc], &ahl[kc]);

    auto dot_ih = [&](int nt) -> f32x4 {
      f32x4 c; c[0] = c[1] = c[2] = c[3] = 0.f;
#pragma unroll
      for (int kc = 0; kc < NKC_X; ++kc) {
        bf16x8 wh = *reinterpret_cast<const bf16x8*>(wlds + (nt * NKC_X + kc) * 512 + lane * 8);
        bf16x8 wl = *reinterpret_cast<const bf16x8*>(wlds + IHL + (nt * NKC_X + kc) * 512 + lane * 8);
        c = mfma16(wh, axl[kc], c);
        c = mfma16(wl, axh[kc], c);
        c = mfma16(wh, axh[kc], c);
      }
      return c;
    };
    auto dot_hh = [&](int nt) -> f32x4 {
      f32x4 c; c[0] = c[1] = c[2] = c[3] = 0.f;
#pragma unroll
      for (int kc = 0; kc < 2; ++kc) {
        bf16x8 wh = *reinterpret_cast<const bf16x8*>(wlds + HH0 + (nt * 2 + kc) * 512 + lane * 8);
        bf16x8 wl = *reinterpret_cast<const bf16x8*>(wlds + HHL + (nt * 2 + kc) * 512 + lane * 8);
        c = mfma16(wh, ahl[kc], c);
        c = mfma16(wl, ahh[kc], c);
        c = mfma16(wh, ahh[kc], c);
      }
      return c;
    };

#pragma unroll 1
    for (int q = 0; q < 4; ++q) {
      f32x4 pr = dot_ih(q);     f32x4 qr = dot_hh(q);
      f32x4 pz = dot_ih(q + 4); f32x4 qz = dot_hh(q + 4);
      f32x4 pn = dot_ih(q + 8); f32x4 qn = dot_hh(q + 8);
      int cb = q * 16 + kb * 4;  // 4 consecutive H columns owned by this lane
      f32x4 bR = *reinterpret_cast<const f32x4*>(ldsB + cb);
      f32x4 bZ = *reinterpret_cast<const f32x4*>(ldsB + 64 + cb);
      f32x4 bI = *reinterpret_cast<const f32x4*>(ldsB + 128 + cb);
      f32x4 bH = *reinterpret_cast<const f32x4*>(ldsB + 192 + cb);
      float* hp = H + (size_t)(row0 + r) * 64 + cb;
      f32x4 hv = *reinterpret_cast<const f32x4*>(hp);
      f32x4 hn;
#pragma unroll
      for (int i = 0; i < 4; ++i) {
        float rg = sigm(pr[i] + qr[i] + bR[i]);
        float zg = sigm(pz[i] + qz[i] + bZ[i]);
        float tn = tanh_fast(pn[i] + bI[i] + rg * (qn[i] + bH[i]));
        hn[i] = (1.f - zg) * tn + zg * hv[i];
      }
      *reinterpret_cast<f32x4*>(hp) = hn;  // aligned float4 store
    }
  }
}

// ---------- fused 2x CSR gather aggregation (grid split over dst ranges) ----------
__global__ __launch_bounds__(256, 6) void aggr_kernel(
    const float* __restrict__ msgA, const int* __restrict__ rpA,
    const int* __restrict__ srcA, float* __restrict__ outA, int NA,
    const float* __restrict__ msgB, const int* __restrict__ rpB,
    const int* __restrict__ srcB, float* __restrict__ outB, int NB) {
  int gtid = blockIdx.x * 256 + threadIdx.x;
  int w = gtid >> 6, lane = gtid & 63;
  int nw = gridDim.x * 4;
  int tot = NA + NB;
  for (int d = w; d < tot; d += nw) {
    const float* msg; const int* rp; const int* srcv; float* out; int dst;
    if (d < NA) { msg = msgA; rp = rpA; srcv = srcA; out = outA; dst = d; }
    else        { msg = msgB; rp = rpB; srcv = srcB; out = outB; dst = d - NA; }
    int p0 = rp[dst], p1 = rp[dst + 1];
    float acc = 0.f;
    int j = p0;
    for (; j + 8 <= p1; j += 8) {
      int s0 = srcv[j],     s1 = srcv[j + 1], s2 = srcv[j + 2], s3 = srcv[j + 3];
      int s4 = srcv[j + 4], s5 = srcv[j + 5], s6 = srcv[j + 6], s7 = srcv[j + 7];
      float a0 = msg[(size_t)s0 * 64 + lane];
      float a1 = msg[(size_t)s1 * 64 + lane];
      float a2 = msg[(size_t)s2 * 64 + lane];
      float a3 = msg[(size_t)s3 * 64 + lane];
      float a4 = msg[(size_t)s4 * 64 + lane];
      float a5 = msg[(size_t)s5 * 64 + lane];
      float a6 = msg[(size_t)s6 * 64 + lane];
      float a7 = msg[(size_t)s7 * 64 + lane];
      acc += a0; acc += a1; acc += a2; acc += a3;
      acc += a4; acc += a5; acc += a6; acc += a7;
    }
    for (; j < p1; ++j) acc += msg[(size_t)srcv[j] * 64 + lane];
    out[(size_t)dst * 64 + lane] = acc;
  }
}

// ---------- CSR build ----------
__global__ void count_kernel(const int* __restrict__ le, const int* __restrict__ ce,
                             int* __restrict__ degL, int* __restrict__ degC, int E) {
  for (int e = blockIdx.x * 256 + threadIdx.x; e < E; e += gridDim.x * 256) {
    atomicAdd(&degL[le[e]], 1);
    atomicAdd(&degC[ce[e]], 1);
  }
}
__global__ void scan_pass1(const int* __restrict__ in, int* __restrict__ bsum, int N, int chunk) {
  int b = blockIdx.x, t = threadIdx.x;
  int base = b * chunk;
  int seg = (chunk + 255) >> 8;
  int a = base + t * seg;
  int e = min(min(N, base + chunk), a + seg);
  int s = 0;
  for (int i = a; i < e; ++i) s += in[i];
  __shared__ int red[256];
  red[t] = s; __syncthreads();
  for (int off = 128; off > 0; off >>= 1) {
    if (t < off) red[t] += red[t + off];
    __syncthreads();
  }
  if (t == 0) bsum[b] = red[0];
}
__global__ void scan_pass2(int* bsum, int* totalOut) {
  __shared__ int sc[256];
  int t = threadIdx.x;
  int v = bsum[t];
  sc[t] = v; __syncthreads();
  for (int off = 1; off < 256; off <<= 1) {
    int u = (t >= off) ? sc[t - off] : 0;
    __syncthreads();
    sc[t] += u;
    __syncthreads();
  }
  bsum[t] = sc[t] - v;
  if (t == 255) *totalOut = sc[255];
}
__global__ void scan_pass3(const int* __restrict__ in, const int* __restrict__ bsum,
                           int* __restrict__ outp, int N, int chunk) {
  int b = blockIdx.x, t = threadIdx.x;
  int base = b * chunk;
  int seg = (chunk + 255) >> 8;
  int a = base + t * seg;
  int e = min(min(N, base + chunk), a + seg);
  int s = 0;
  for (int i = a; i < e; ++i) s += in[i];
  __shared__ int sc[256];
  int v = s;
  sc[t] = v; __syncthreads();
  for (int off = 1; off < 256; off <<= 1) {
    int u = (t >= off) ? sc[t - off] : 0;
    __syncthreads();
    sc[t] += u;
    __syncthreads();
  }
  int run = bsum[b] + sc[t] - v;
  for (int i = a; i < e; ++i) { outp[i] = run; run += in[i]; }
}
__global__ void fill_kernel(const int* __restrict__ le, const int* __restrict__ ce,
                            int* __restrict__ curL, int* __restrict__ curC,
                            int* __restrict__ srcL2C, int* __restrict__ srcC2L, int E) {
  for (int e = blockIdx.x * 256 + threadIdx.x; e < E; e += gridDim.x * 256) {
    int ls = le[e], cd = ce[e];
    int s1 = atomicAdd(&curC[cd], 1);
    srcL2C[s1] = ls;
    int s2 = atomicAdd(&curL[ls], 1);
    srcC2L[s2] = cd;
  }
}

// ---------- init / readout ----------
__global__ void init_emb(float* __restrict__ emb, const float* __restrict__ ini, int n) {
  for (int i = blockIdx.x * 256 + threadIdx.x; i < n; i += gridDim.x * 256)
    emb[i] = ini[i & 63];
}
__global__ void readout_sum(const float* __restrict__ lemb, const int* __restrict__ lb,
                            float* __restrict__ gsum, float* __restrict__ gcnt, int L) {
  int gtid = blockIdx.x * 256 + threadIdx.x;
  int w = gtid >> 6, lane = gtid & 63;
  int nw = gridDim.x * 4;
  int chunk = (L + nw - 1) / nw;
  int s = w * chunk, e = min(L, s + chunk);
  if (s >= e) return;
  float acc = 0.f, cnt = 0.f;
  int curb = lb[s];
  for (int row = s; row < e; ++row) {
    int b = lb[row];
    if (b != curb) {
      atomicAdd(&gsum[curb * 64 + lane], acc);
      if (lane == 0) atomicAdd(&gcnt[curb], cnt);
      acc = 0.f; cnt = 0.f; curb = b;
    }
    acc += lemb[(size_t)row * 64 + lane];
    cnt += 1.f;
  }
  atomicAdd(&gsum[curb * 64 + lane], acc);
  if (lane == 0) atomicAdd(&gcnt[curb], cnt);
}
__global__ void final_kernel(const float* __restrict__ gsum, const float* __restrict__ gcnt,
                             const float* __restrict__ W1, const float* __restrict__ B1,
                             const float* __restrict__ W2, const float* __restrict__ B2,
                             float* __restrict__ outp) {
  __shared__ float w1s[4096];
  __shared__ float w2s[64];
  int t = threadIdx.x;  // 128 threads: one per graph
  for (int i = t; i < 4096; i += 128) w1s[i] = W1[i];
  if (t < 64) w2s[t] = W2[t];
  __syncthreads();
  float x[64];
  float c = fmaxf(gcnt[t], 1.f);
#pragma unroll
  for (int d = 0; d < 64; ++d) x[d] = gsum[t * 64 + d] / c;
  float acc = B2[0];
  for (int j = 0; j < 64; ++j) {
    float h = B1[j];
#pragma unroll
    for (int k = 0; k < 64; ++k) h += x[k] * w1s[j * 64 + k];
    acc += fmaxf(h, 0.f) * w2s[j];
  }
  outp[t] = 1.f / (1.f + __expf(-acc));
}

// ---------- launch ----------
extern "C" void kernel_launch(void* const* d_in, const int* in_sizes, int n_in,
                              void* d_out, int out_size, void* d_ws, size_t ws_size,
                              hipStream_t stream) {
  const int* le = (const int*)d_in[2];
  const int* ce = (const int*)d_in[3];
  const int* lb = (const int*)d_in[4];
  const float* l_init = (const float*)d_in[5];
  const float* c_init = (const float*)d_in[6];
  const float* l2c_W1 = (const float*)d_in[7];
  const float* l2c_b1 = (const float*)d_in[8];
  const float* l2c_W2 = (const float*)d_in[9];
  const float* l2c_b2 = (const float*)d_in[10];
  const float* c2l_W1 = (const float*)d_in[11];
  const float* c2l_b1 = (const float*)d_in[12];
  const float* c2l_W2 = (const float*)d_in[13];
  const float* c2l_b2 = (const float*)d_in[14];
  const float* gc_Wih = (const float*)d_in[15];
  const float* gc_Whh = (const float*)d_in[16];
  const float* gc_bih = (const float*)d_in[17];
  const float* gc_bhh = (const float*)d_in[18];
  const float* gl_Wih = (const float*)d_in[19];
  const float* gl_Whh = (const float*)d_in[20];
  const float* gl_bih = (const float*)d_in[21];
  const float* gl_bhh = (const float*)d_in[22];
  const float* ro_W1 = (const float*)d_in[23];
  const float* ro_b1 = (const float*)d_in[24];
  const float* ro_W2 = (const float*)d_in[25];
  const float* ro_b2 = (const float*)d_in[26];
  const int E = in_sizes[2];
  const int L = in_sizes[4];
  const int C = 100000;

  char* p = (char*)d_ws;
  auto alloc = [&](size_t b) -> char* {
    char* r = p;
    p += (b + 255) & ~(size_t)255;
    return r;
  };
  float* l_emb = (float*)alloc((size_t)L * 64 * 4);
  float* c_emb = (float*)alloc((size_t)C * 64 * 4);
  float* l_msg = (float*)alloc((size_t)L * 64 * 4);
  float* c_msg = (float*)alloc((size_t)C * 64 * 4);
  float* l2c_aggr = (float*)alloc((size_t)C * 64 * 4);
  float* c2l_aggr = (float*)alloc((size_t)L * 64 * 4);
  int* rowptrC = (int*)alloc((size_t)(C + 1) * 4);
  int* rowptrL = (int*)alloc((size_t)(L + 1) * 4);
  int* curC = (int*)alloc((size_t)C * 4);
  int* curL = (int*)alloc((size_t)L * 4);
  int* srcL2C = (int*)alloc((size_t)E * 4);
  int* srcC2L = (int*)alloc((size_t)E * 4);
  int* bsum = (int*)alloc(256 * 4);
  float* gsum = (float*)alloc(128 * 64 * 4);
  float* gcnt = (float*)alloc(128 * 4);
  unsigned short* gGl = (unsigned short*)alloc(73728 * 2);
  unsigned short* gGc = (unsigned short*)alloc(49152 * 2);
  unsigned short* gMl = (unsigned short*)alloc(16384 * 2);
  unsigned short* gMc = (unsigned short*)alloc(16384 * 2);

  // weight prep (once per launch)
  prep_split<<<8, 256, 0, stream>>>(gl_Wih, gl_Whh, gc_Wih, gc_Whh,
                                    l2c_W1, l2c_W2, c2l_W1, c2l_W2,
                                    gGl, gGc, gMl, gMc);

  // CSR build (once per launch; reused by all 16 aggregations)
  hipMemsetAsync(curC, 0, (size_t)C * 4, stream);
  hipMemsetAsync(curL, 0, (size_t)L * 4, stream);
  count_kernel<<<512, 256, 0, stream>>>(le, ce, curL, curC, E);
  int chC = (C + 255) / 256, chL = (L + 255) / 256;
  scan_pass1<<<256, 256, 0, stream>>>(curC, bsum, C, chC);
  scan_pass2<<<1, 256, 0, stream>>>(bsum, rowptrC + C);
  scan_pass3<<<256, 256, 0, stream>>>(curC, bsum, rowptrC, C, chC);
  scan_pass1<<<256, 256, 0, stream>>>(curL, bsum, L, chL);
  scan_pass2<<<1, 256, 0, stream>>>(bsum, rowptrL + L);
  scan_pass3<<<256, 256, 0, stream>>>(curL, bsum, rowptrL, L, chL);
  hipMemcpyAsync(curC, rowptrC, (size_t)C * 4, hipMemcpyDeviceToDevice, stream);
  hipMemcpyAsync(curL, rowptrL, (size_t)L * 4, hipMemcpyDeviceToDevice, stream);
  fill_kernel<<<512, 256, 0, stream>>>(le, ce, curL, curC, srcL2C, srcC2L, E);

  init_emb<<<1024, 256, 0, stream>>>(l_emb, l_init, L * 64);
  init_emb<<<1024, 256, 0, stream>>>(c_emb, c_init, C * 64);

  int TL = L >> 4, TC = C >> 4;
  for (int it = 0; it < 8; ++it) {
    mlp_kernel<<<768, 256, 0, stream>>>(l_emb, l_msg, TL, gMl, l2c_b1, l2c_b2,
                                        c_emb, c_msg, TC, gMc, c2l_b1, c2l_b2, 512);
    aggr_kernel<<<2048, 256, 0, stream>>>(l_msg, rowptrC, srcL2C, l2c_aggr, C,
                                          c_msg, rowptrL, srcC2L, c2l_aggr, L);
    gru_kernel<64><<<256, 512, 0, stream>>>(l2c_aggr, c_emb, gGc, gc_bih, gc_bhh, C);
    gru_kernel<128><<<256, 512, 0, stream>>>(c2l_aggr, l_emb, gGl, gl_bih, gl_bhh, L);
  }

  hipMemsetAsync(gsum, 0, 128 * 64 * 4, stream);
  hipMemsetAsync(gcnt, 0, 128 * 4, stream);
  readout_sum<<<512, 256, 0, stream>>>(l_emb, lb, gsum, gcnt, L);
  final_kernel<<<1, 128, 0, stream>>>(gsum, gcnt, ro_W1, ro_b1, ro_W2, ro_b2,
                                      (float*)d_out);
}

// Round 10
// 2599.968 us; speedup vs baseline: 3.9585x; 1.1786x over previous
//
#include <hip/hip_runtime.h>
#include <stdint.h>

// ---------- types / helpers ----------
typedef short bf16x8 __attribute__((ext_vector_type(8)));   // 8 bf16 = 4 VGPR (MFMA A/B frag)
typedef float f32x4  __attribute__((ext_vector_type(4)));   // MFMA C/D frag

__device__ __forceinline__ unsigned short f2bf(float x) {
  unsigned int u = __builtin_bit_cast(unsigned int, x);
  u += 0x7fffu + ((u >> 16) & 1u);
  return (unsigned short)(u >> 16);
}
__device__ __forceinline__ float bf2f(unsigned short b) {
  unsigned int u = ((unsigned int)b) << 16;
  return __builtin_bit_cast(float, u);
}
__device__ __forceinline__ f32x4 mfma16(bf16x8 a, bf16x8 b, f32x4 c) {
  return __builtin_amdgcn_mfma_f32_16x16x32_bf16(a, b, c, 0, 0, 0);
}
// load 8 consecutive f32, split into hi/lo bf16 (hi+lo ~ f32-exact)
__device__ __forceinline__ void split8(const float* __restrict__ p, bf16x8* h, bf16x8* l) {
  float4 a = *reinterpret_cast<const float4*>(p);
  float4 b = *reinterpret_cast<const float4*>(p + 4);
  float v[8] = {a.x, a.y, a.z, a.w, b.x, b.y, b.z, b.w};
  bf16x8 hh, ll;
#pragma unroll
  for (int i = 0; i < 8; ++i) {
    unsigned short hb = f2bf(v[i]);
    hh[i] = (short)hb;
    ll[i] = (short)f2bf(v[i] - bf2f(hb));
  }
  *h = hh; *l = ll;
}
__device__ __forceinline__ float fexp(float x) {  // e^x via v_exp_f32
  return __builtin_amdgcn_exp2f(x * 1.4426950408889634f);
}
__device__ __forceinline__ float sigm(float x) {
  return __builtin_amdgcn_rcpf(1.f + fexp(-x));
}
__device__ __forceinline__ float tanh_fast(float x) {
  x = fminf(fmaxf(x, -15.f), 15.f);
  float e2 = fexp(2.f * x);
  return (e2 - 1.f) * __builtin_amdgcn_rcpf(e2 + 1.f);
}

// ---------- weight prep: split f32 weights into frag-ordered bf16 hi/lo (once) ----------
// gGl layout (ushort): ihH[0,24576) ihL[24576,49152) hhH[49152,61440) hhL[61440,73728)
// gGc layout:          ihH[0,12288) ihL[12288,24576) hhH[24576,36864) hhL[36864,49152)
// gMl/gMc layout:      W1H[0,4096)  W1L[4096,8192)   W2H[8192,12288)  W2L[12288,16384)
__global__ void prep_split(const float* __restrict__ glWih, const float* __restrict__ glWhh,
                           const float* __restrict__ gcWih, const float* __restrict__ gcWhh,
                           const float* __restrict__ mlW1, const float* __restrict__ mlW2,
                           const float* __restrict__ mcW1, const float* __restrict__ mcW2,
                           unsigned short* __restrict__ gGl, unsigned short* __restrict__ gGc,
                           unsigned short* __restrict__ gMl, unsigned short* __restrict__ gMc) {
  int b = blockIdx.x, t = threadIdx.x;
  const float* src; unsigned short *dh, *dl; int NT, KX;
  switch (b) {
    case 0: src = glWih; dh = gGl;         dl = gGl + 24576; NT = 12; KX = 128; break;
    case 1: src = glWhh; dh = gGl + 49152; dl = gGl + 61440; NT = 12; KX = 64;  break;
    case 2: src = gcWih; dh = gGc;         dl = gGc + 12288; NT = 12; KX = 64;  break;
    case 3: src = gcWhh; dh = gGc + 24576; dl = gGc + 36864; NT = 12; KX = 64;  break;
    case 4: src = mlW1;  dh = gMl;         dl = gMl + 4096;  NT = 4;  KX = 64;  break;
    case 5: src = mlW2;  dh = gMl + 8192;  dl = gMl + 12288; NT = 4;  KX = 64;  break;
    case 6: src = mcW1;  dh = gMc;         dl = gMc + 4096;  NT = 4;  KX = 64;  break;
    default: src = mcW2; dh = gMc + 8192;  dl = gMc + 12288; NT = 4;  KX = 64;  break;
  }
  int NKC = KX / 32;
  int tot = NT * NKC * 64;
  for (int e = t; e < tot; e += 256) {
    int f = e >> 6, l = e & 63;
    int nt = f / NKC, kc = f % NKC;
    int n = nt * 16 + (l & 15), k0 = kc * 32 + (l >> 4) * 8;
    bf16x8 h, lo;
    split8(src + n * KX + k0, &h, &lo);
    *reinterpret_cast<bf16x8*>(dh + e * 8) = h;
    *reinterpret_cast<bf16x8*>(dl + e * 8) = lo;
  }
}

// ---------- fused 2x MLP (grid split), operand-swapped MFMA: D = W·X^T ----------
// lane holds one x-row (lane&15) and 4 consecutive n-cols ((lane>>4)*4+i) -> float4 stores.
__global__ __launch_bounds__(256, 3) void mlp_kernel(
    const float* __restrict__ X1, float* __restrict__ Y1, int T1,
    const unsigned short* __restrict__ g1, const float* __restrict__ B11, const float* __restrict__ B21,
    const float* __restrict__ X2, float* __restrict__ Y2, int T2,
    const unsigned short* __restrict__ g2, const float* __restrict__ B12, const float* __restrict__ B22,
    int G1) {
  const float* X; float* Y; int tiles, b, nb;
  const unsigned short* gw; const float *B1, *B2;
  if ((int)blockIdx.x < G1) {
    X = X1; Y = Y1; tiles = T1; gw = g1; B1 = B11; B2 = B21; b = blockIdx.x; nb = G1;
  } else {
    X = X2; Y = Y2; tiles = T2; gw = g2; B1 = B12; B2 = B22; b = blockIdx.x - G1; nb = gridDim.x - G1;
  }
  __shared__ __align__(16) unsigned short wbuf[16384];
  __shared__ __align__(16) float hbuf[4][16 * 68];
  int tid = threadIdx.x, wid = tid >> 6, lane = tid & 63;
  int r = lane & 15, kb = lane >> 4;
  for (int i4 = tid; i4 < 2048; i4 += 256)
    *reinterpret_cast<int4*>(wbuf + i4 * 8) = *reinterpret_cast<const int4*>(gw + i4 * 8);
  __syncthreads();
  const unsigned short *w1h = wbuf, *w1l = wbuf + 4096, *w2h = wbuf + 8192, *w2l = wbuf + 12288;
  f32x4 b1f[4], b2f[4];
#pragma unroll
  for (int nt = 0; nt < 4; ++nt) {
    b1f[nt] = *reinterpret_cast<const f32x4*>(B1 + nt * 16 + kb * 4);
    b2f[nt] = *reinterpret_cast<const f32x4*>(B2 + nt * 16 + kb * 4);
  }
  float* hl = hbuf[wid];
  for (int t = b * 4 + wid; t < tiles; t += nb * 4) {
    int row0 = t << 4;
    const float* xp = X + (size_t)(row0 + r) * 64 + kb * 8;
    bf16x8 a0h, a0l, a1h, a1l;
    split8(xp, &a0h, &a0l);
    split8(xp + 32, &a1h, &a1l);
#pragma unroll
    for (int nt = 0; nt < 4; ++nt) {
      f32x4 c = b1f[nt];
      bf16x8 wh = *reinterpret_cast<const bf16x8*>(w1h + ((nt * 2 + 0) * 64 + lane) * 8);
      bf16x8 wl = *reinterpret_cast<const bf16x8*>(w1l + ((nt * 2 + 0) * 64 + lane) * 8);
      c = mfma16(wh, a0l, c); c = mfma16(wl, a0h, c); c = mfma16(wh, a0h, c);
      wh = *reinterpret_cast<const bf16x8*>(w1h + ((nt * 2 + 1) * 64 + lane) * 8);
      wl = *reinterpret_cast<const bf16x8*>(w1l + ((nt * 2 + 1) * 64 + lane) * 8);
      c = mfma16(wh, a1l, c); c = mfma16(wl, a1h, c); c = mfma16(wh, a1h, c);
#pragma unroll
      for (int i = 0; i < 4; ++i) c[i] = fmaxf(c[i], 0.f);
      *reinterpret_cast<f32x4*>(hl + r * 68 + nt * 16 + kb * 4) = c;  // b128 write, own row
    }
    // same-wave LDS RAW: DS pipe is in-order within a wave
    bf16x8 h0h, h0l, h1h, h1l;
    split8(hl + r * 68 + kb * 8, &h0h, &h0l);
    split8(hl + r * 68 + 32 + kb * 8, &h1h, &h1l);
    float* yp = Y + (size_t)row0 * 64;
#pragma unroll
    for (int nt = 0; nt < 4; ++nt) {
      f32x4 c = b2f[nt];
      bf16x8 wh = *reinterpret_cast<const bf16x8*>(w2h + ((nt * 2 + 0) * 64 + lane) * 8);
      bf16x8 wl = *reinterpret_cast<const bf16x8*>(w2l + ((nt * 2 + 0) * 64 + lane) * 8);
      c = mfma16(wh, h0l, c); c = mfma16(wl, h0h, c); c = mfma16(wh, h0h, c);
      wh = *reinterpret_cast<const bf16x8*>(w2h + ((nt * 2 + 1) * 64 + lane) * 8);
      wl = *reinterpret_cast<const bf16x8*>(w2l + ((nt * 2 + 1) * 64 + lane) * 8);
      c = mfma16(wh, h1l, c); c = mfma16(wl, h1h, c); c = mfma16(wh, h1h, c);
      *reinterpret_cast<f32x4*>(yp + (size_t)r * 64 + nt * 16 + kb * 4) = c;  // float4 store
    }
  }
}

// ---------- GRU cell, in place, hi/lo 3-term, swapped MFMA, LDS weights ----------
// 512 threads, min-1-wave bound. q loop NOT unrolled: keeps live set + scheduler
// temporaries inside 128 VGPR (fully unrolled version spilled ~250 MB/dispatch).
template <int KX>
__global__ __launch_bounds__(512, 1) void gru_kernel(
    const float* __restrict__ Xa, float* __restrict__ H,
    const unsigned short* __restrict__ gws,
    const float* __restrict__ Bih, const float* __restrict__ Bhh, int M) {
  constexpr int NKC_X = KX / 32;
  constexpr int NFX = 12 * NKC_X;
  constexpr int IHL = NFX * 512;       // ihL offset (ushorts)
  constexpr int HH0 = 2 * NFX * 512;   // hhH
  constexpr int HHL = HH0 + 12288;     // hhL
  constexpr int TOTU = HH0 + 24576;
  __shared__ __align__(16) unsigned short wlds[TOTU];
  __shared__ __align__(16) float ldsB[256];  // [0,64) r-sum [64,128) z-sum [128,192) bnI [192,256) bnH
  int tid = threadIdx.x;
  for (int i4 = tid; i4 < TOTU / 8; i4 += 512)
    *reinterpret_cast<int4*>(wlds + i4 * 8) = *reinterpret_cast<const int4*>(gws + i4 * 8);
  if (tid < 128) ldsB[tid] = Bih[tid] + Bhh[tid];
  else if (tid < 192) ldsB[tid] = Bih[tid];            // bnI: Bih[128+j] at ldsB[128+j]
  else if (tid < 256) ldsB[tid] = Bhh[tid - 64];       // bnH: Bhh[128+j] at ldsB[192+j]
  __syncthreads();
  int wid = tid >> 6, lane = tid & 63;
  int r = lane & 15, kb = lane >> 4;
  int tiles = M >> 4;
  for (int t = blockIdx.x * 8 + wid; t < tiles; t += gridDim.x * 8) {
    int row0 = t << 4;
    bf16x8 axh[NKC_X], axl[NKC_X], ahh[2], ahl[2];
#pragma unroll
    for (int kc = 0; kc < 2; ++kc)
      split8(Xa + (size_t)(row0 + r) * 64 + kc * 32 + kb * 8, &axh[kc], &axl[kc]);
    if (KX == 128) {
#pragma unroll
      for (int kc = 0; kc < 2; ++kc)  // pair-flip lives inside this 16-row tile
        split8(H + (size_t)((row0 + r) ^ 1) * 64 + kc * 32 + kb * 8, &axh[2 + kc], &axl[2 + kc]);
    }
#pragma unroll
    for (int kc = 0; kc < 2; ++kc)
      split8(H + (size_t)(row0 + r) * 64 + kc * 32 + kb * 8, &ahh[kc], &ahl[kc]);

    auto dot_ih = [&](int nt) -> f32x4 {
      f32x4 c; c[0] = c[1] = c[2] = c[3] = 0.f;
#pragma unroll
      for (int kc = 0; kc < NKC_X; ++kc) {
        bf16x8 wh = *reinterpret_cast<const bf16x8*>(wlds + (nt * NKC_X + kc) * 512 + lane * 8);
        bf16x8 wl = *reinterpret_cast<const bf16x8*>(wlds + IHL + (nt * NKC_X + kc) * 512 + lane * 8);
        c = mfma16(wh, axl[kc], c);
        c = mfma16(wl, axh[kc], c);
        c = mfma16(wh, axh[kc], c);
      }
      return c;
    };
    auto dot_hh = [&](int nt) -> f32x4 {
      f32x4 c; c[0] = c[1] = c[2] = c[3] = 0.f;
#pragma unroll
      for (int kc = 0; kc < 2; ++kc) {
        bf16x8 wh = *reinterpret_cast<const bf16x8*>(wlds + HH0 + (nt * 2 + kc) * 512 + lane * 8);
        bf16x8 wl = *reinterpret_cast<const bf16x8*>(wlds + HHL + (nt * 2 + kc) * 512 + lane * 8);
        c = mfma16(wh, ahl[kc], c);
        c = mfma16(wl, ahh[kc], c);
        c = mfma16(wh, ahh[kc], c);
      }
      return c;
    };

#pragma unroll 1
    for (int q = 0; q < 4; ++q) {
      f32x4 pr = dot_ih(q);     f32x4 qr = dot_hh(q);
      f32x4 pz = dot_ih(q + 4); f32x4 qz = dot_hh(q + 4);
      f32x4 pn = dot_ih(q + 8); f32x4 qn = dot_hh(q + 8);
      int cb = q * 16 + kb * 4;  // 4 consecutive H columns owned by this lane
      f32x4 bR = *reinterpret_cast<const f32x4*>(ldsB + cb);
      f32x4 bZ = *reinterpret_cast<const f32x4*>(ldsB + 64 + cb);
      f32x4 bI = *reinterpret_cast<const f32x4*>(ldsB + 128 + cb);
      f32x4 bH = *reinterpret_cast<const f32x4*>(ldsB + 192 + cb);
      float* hp = H + (size_t)(row0 + r) * 64 + cb;
      f32x4 hv = *reinterpret_cast<const f32x4*>(hp);
      f32x4 hn;
#pragma unroll
      for (int i = 0; i < 4; ++i) {
        float rg = sigm(pr[i] + qr[i] + bR[i]);
        float zg = sigm(pz[i] + qz[i] + bZ[i]);
        float tn = tanh_fast(pn[i] + bI[i] + rg * (qn[i] + bH[i]));
        hn[i] = (1.f - zg) * tn + zg * hv[i];
      }
      *reinterpret_cast<f32x4*>(hp) = hn;  // aligned float4 store
    }
  }
}

// ---------- fused 2x CSR gather aggregation, float4 lanes: 4 edges in flight/load ----------
// lane: quarter q=lane>>4 handles edge j+q; cols (lane&15)*4..+3. Cross-quarter shfl reduce.
__global__ __launch_bounds__(256, 4) void aggr_kernel(
    const float* __restrict__ msgA, const int* __restrict__ rpA,
    const int* __restrict__ srcA, float* __restrict__ outA, int NA,
    const float* __restrict__ msgB, const int* __restrict__ rpB,
    const int* __restrict__ srcB, float* __restrict__ outB, int NB) {
  int gtid = blockIdx.x * 256 + threadIdx.x;
  int w = gtid >> 6, lane = gtid & 63;
  int q = lane >> 4, c = (lane & 15) * 4;
  int nw = gridDim.x * 4;
  int tot = NA + NB;
  for (int d = w; d < tot; d += nw) {
    const float* msg; const int* rp; const int* srcv; float* out; int dst;
    if (d < NA) { msg = msgA; rp = rpA; srcv = srcA; out = outA; dst = d; }
    else        { msg = msgB; rp = rpB; srcv = srcB; out = outB; dst = d - NA; }
    int p0 = rp[dst], p1 = rp[dst + 1];
    f32x4 acc0; acc0[0] = acc0[1] = acc0[2] = acc0[3] = 0.f;
    f32x4 acc1; acc1[0] = acc1[1] = acc1[2] = acc1[3] = 0.f;
    int j = p0;
    for (; j + 8 <= p1; j += 8) {
      int s0 = srcv[j + q];
      int s1 = srcv[j + 4 + q];
      float4 v0 = *reinterpret_cast<const float4*>(msg + (size_t)s0 * 64 + c);
      float4 v1 = *reinterpret_cast<const float4*>(msg + (size_t)s1 * 64 + c);
      acc0[0] += v0.x; acc0[1] += v0.y; acc0[2] += v0.z; acc0[3] += v0.w;
      acc1[0] += v1.x; acc1[1] += v1.y; acc1[2] += v1.z; acc1[3] += v1.w;
    }
    if (j + q < p1) {  // tail group 0 (predicated per quarter)
      int s = srcv[j + q];
      float4 v = *reinterpret_cast<const float4*>(msg + (size_t)s * 64 + c);
      acc0[0] += v.x; acc0[1] += v.y; acc0[2] += v.z; acc0[3] += v.w;
    }
    if (j + 4 + q < p1) {  // tail group 1
      int s = srcv[j + 4 + q];
      float4 v = *reinterpret_cast<const float4*>(msg + (size_t)s * 64 + c);
      acc1[0] += v.x; acc1[1] += v.y; acc1[2] += v.z; acc1[3] += v.w;
    }
#pragma unroll
    for (int i = 0; i < 4; ++i) {
      float a = acc0[i] + acc1[i];
      a += __shfl_xor(a, 16, 64);
      a += __shfl_xor(a, 32, 64);
      acc0[i] = a;
    }
    if (q == 0) {
      float4 o; o.x = acc0[0]; o.y = acc0[1]; o.z = acc0[2]; o.w = acc0[3];
      *reinterpret_cast<float4*>(out + (size_t)dst * 64 + c) = o;
    }
  }
}

// ---------- CSR build (rank captured at count time -> atomic-free fill) ----------
__global__ void count_kernel(const int* __restrict__ le, const int* __restrict__ ce,
                             int* __restrict__ degL, int* __restrict__ degC,
                             int* __restrict__ rankL, int* __restrict__ rankC, int E) {
  for (int e = blockIdx.x * 256 + threadIdx.x; e < E; e += gridDim.x * 256) {
    rankL[e] = atomicAdd(&degL[le[e]], 1);
    rankC[e] = atomicAdd(&degC[ce[e]], 1);
  }
}
__global__ void scan_pass1(const int* __restrict__ in, int* __restrict__ bsum, int N, int chunk) {
  int b = blockIdx.x, t = threadIdx.x;
  int base = b * chunk;
  int seg = (chunk + 255) >> 8;
  int a = base + t * seg;
  int e = min(min(N, base + chunk), a + seg);
  int s = 0;
  for (int i = a; i < e; ++i) s += in[i];
  __shared__ int red[256];
  red[t] = s; __syncthreads();
  for (int off = 128; off > 0; off >>= 1) {
    if (t < off) red[t] += red[t + off];
    __syncthreads();
  }
  if (t == 0) bsum[b] = red[0];
}
__global__ void scan_pass2(int* bsum, int* totalOut) {
  __shared__ int sc[256];
  int t = threadIdx.x;
  int v = bsum[t];
  sc[t] = v; __syncthreads();
  for (int off = 1; off < 256; off <<= 1) {
    int u = (t >= off) ? sc[t - off] : 0;
    __syncthreads();
    sc[t] += u;
    __syncthreads();
  }
  bsum[t] = sc[t] - v;
  if (t == 255) *totalOut = sc[255];
}
__global__ void scan_pass3(const int* __restrict__ in, const int* __restrict__ bsum,
                           int* __restrict__ outp, int N, int chunk) {
  int b = blockIdx.x, t = threadIdx.x;
  int base = b * chunk;
  int seg = (chunk + 255) >> 8;
  int a = base + t * seg;
  int e = min(min(N, base + chunk), a + seg);
  int s = 0;
  for (int i = a; i < e; ++i) s += in[i];
  __shared__ int sc[256];
  int v = s;
  sc[t] = v; __syncthreads();
  for (int off = 1; off < 256; off <<= 1) {
    int u = (t >= off) ? sc[t - off] : 0;
    __syncthreads();
    sc[t] += u;
    __syncthreads();
  }
  int run = bsum[b] + sc[t] - v;
  for (int i = a; i < e; ++i) { outp[i] = run; run += in[i]; }
}
__global__ void fill_kernel(const int* __restrict__ le, const int* __restrict__ ce,
                            const int* __restrict__ rowptrL, const int* __restrict__ rowptrC,
                            const int* __restrict__ rankL, const int* __restrict__ rankC,
                            int* __restrict__ srcL2C, int* __restrict__ srcC2L, int E) {
  for (int e = blockIdx.x * 256 + threadIdx.x; e < E; e += gridDim.x * 256) {
    int ls = le[e], cd = ce[e];
    srcL2C[rowptrC[cd] + rankC[e]] = ls;
    srcC2L[rowptrL[ls] + rankL[e]] = cd;
  }
}

// ---------- init / readout ----------
__global__ void init_emb(float* __restrict__ emb, const float* __restrict__ ini, int n) {
  for (int i = blockIdx.x * 256 + threadIdx.x; i < n; i += gridDim.x * 256)
    emb[i] = ini[i & 63];
}
__global__ void readout_sum(const float* __restrict__ lemb, const int* __restrict__ lb,
                            float* __restrict__ gsum, float* __restrict__ gcnt, int L) {
  int gtid = blockIdx.x * 256 + threadIdx.x;
  int w = gtid >> 6, lane = gtid & 63;
  int nw = gridDim.x * 4;
  int chunk = (L + nw - 1) / nw;
  int s = w * chunk, e = min(L, s + chunk);
  if (s >= e) return;
  float acc = 0.f, cnt = 0.f;
  int curb = lb[s];
  for (int row = s; row < e; ++row) {
    int b = lb[row];
    if (b != curb) {
      atomicAdd(&gsum[curb * 64 + lane], acc);
      if (lane == 0) atomicAdd(&gcnt[curb], cnt);
      acc = 0.f; cnt = 0.f; curb = b;
    }
    acc += lemb[(size_t)row * 64 + lane];
    cnt += 1.f;
  }
  atomicAdd(&gsum[curb * 64 + lane], acc);
  if (lane == 0) atomicAdd(&gcnt[curb], cnt);
}
__global__ void final_kernel(const float* __restrict__ gsum, const float* __restrict__ gcnt,
                             const float* __restrict__ W1, const float* __restrict__ B1,
                             const float* __restrict__ W2, const float* __restrict__ B2,
                             float* __restrict__ outp) {
  __shared__ float w1s[4096];
  __shared__ float w2s[64];
  int t = threadIdx.x;  // 128 threads: one per graph
  for (int i = t; i < 4096; i += 128) w1s[i] = W1[i];
  if (t < 64) w2s[t] = W2[t];
  __syncthreads();
  float x[64];
  float c = fmaxf(gcnt[t], 1.f);
#pragma unroll
  for (int d = 0; d < 64; ++d) x[d] = gsum[t * 64 + d] / c;
  float acc = B2[0];
  for (int j = 0; j < 64; ++j) {
    float h = B1[j];
#pragma unroll
    for (int k = 0; k < 64; ++k) h += x[k] * w1s[j * 64 + k];
    acc += fmaxf(h, 0.f) * w2s[j];
  }
  outp[t] = 1.f / (1.f + __expf(-acc));
}

// ---------- launch ----------
extern "C" void kernel_launch(void* const* d_in, const int* in_sizes, int n_in,
                              void* d_out, int out_size, void* d_ws, size_t ws_size,
                              hipStream_t stream) {
  const int* le = (const int*)d_in[2];
  const int* ce = (const int*)d_in[3];
  const int* lb = (const int*)d_in[4];
  const float* l_init = (const float*)d_in[5];
  const float* c_init = (const float*)d_in[6];
  const float* l2c_W1 = (const float*)d_in[7];
  const float* l2c_b1 = (const float*)d_in[8];
  const float* l2c_W2 = (const float*)d_in[9];
  const float* l2c_b2 = (const float*)d_in[10];
  const float* c2l_W1 = (const float*)d_in[11];
  const float* c2l_b1 = (const float*)d_in[12];
  const float* c2l_W2 = (const float*)d_in[13];
  const float* c2l_b2 = (const float*)d_in[14];
  const float* gc_Wih = (const float*)d_in[15];
  const float* gc_Whh = (const float*)d_in[16];
  const float* gc_bih = (const float*)d_in[17];
  const float* gc_bhh = (const float*)d_in[18];
  const float* gl_Wih = (const float*)d_in[19];
  const float* gl_Whh = (const float*)d_in[20];
  const float* gl_bih = (const float*)d_in[21];
  const float* gl_bhh = (const float*)d_in[22];
  const float* ro_W1 = (const float*)d_in[23];
  const float* ro_b1 = (const float*)d_in[24];
  const float* ro_W2 = (const float*)d_in[25];
  const float* ro_b2 = (const float*)d_in[26];
  const int E = in_sizes[2];
  const int L = in_sizes[4];
  const int C = 100000;

  char* p = (char*)d_ws;
  auto alloc = [&](size_t b) -> char* {
    char* r = p;
    p += (b + 255) & ~(size_t)255;
    return r;
  };
  float* l_emb = (float*)alloc((size_t)L * 64 * 4);
  float* c_emb = (float*)alloc((size_t)C * 64 * 4);
  float* l_msg = (float*)alloc((size_t)L * 64 * 4);
  float* c_msg = (float*)alloc((size_t)C * 64 * 4);
  float* l2c_aggr = (float*)alloc((size_t)C * 64 * 4);
  float* c2l_aggr = (float*)alloc((size_t)L * 64 * 4);
  int* rowptrC = (int*)alloc((size_t)(C + 1) * 4);
  int* rowptrL = (int*)alloc((size_t)(L + 1) * 4);
  int* degC = (int*)alloc((size_t)C * 4);
  int* degL = (int*)alloc((size_t)L * 4);
  int* srcL2C = (int*)alloc((size_t)E * 4);
  int* srcC2L = (int*)alloc((size_t)E * 4);
  int* rankL = (int*)alloc((size_t)E * 4);
  int* rankC = (int*)alloc((size_t)E * 4);
  int* bsum = (int*)alloc(256 * 4);
  float* gsum = (float*)alloc(128 * 64 * 4);
  float* gcnt = (float*)alloc(128 * 4);
  unsigned short* gGl = (unsigned short*)alloc(73728 * 2);
  unsigned short* gGc = (unsigned short*)alloc(49152 * 2);
  unsigned short* gMl = (unsigned short*)alloc(16384 * 2);
  unsigned short* gMc = (unsigned short*)alloc(16384 * 2);

  // weight prep (once per launch)
  prep_split<<<8, 256, 0, stream>>>(gl_Wih, gl_Whh, gc_Wih, gc_Whh,
                                    l2c_W1, l2c_W2, c2l_W1, c2l_W2,
                                    gGl, gGc, gMl, gMc);

  // CSR build (once per launch; reused by all 16 aggregations)
  hipMemsetAsync(degC, 0, (size_t)C * 4, stream);
  hipMemsetAsync(degL, 0, (size_t)L * 4, stream);
  count_kernel<<<512, 256, 0, stream>>>(le, ce, degL, degC, rankL, rankC, E);
  int chC = (C + 255) / 256, chL = (L + 255) / 256;
  scan_pass1<<<256, 256, 0, stream>>>(degC, bsum, C, chC);
  scan_pass2<<<1, 256, 0, stream>>>(bsum, rowptrC + C);
  scan_pass3<<<256, 256, 0, stream>>>(degC, bsum, rowptrC, C, chC);
  scan_pass1<<<256, 256, 0, stream>>>(degL, bsum, L, chL);
  scan_pass2<<<1, 256, 0, stream>>>(bsum, rowptrL + L);
  scan_pass3<<<256, 256, 0, stream>>>(degL, bsum, rowptrL, L, chL);
  fill_kernel<<<512, 256, 0, stream>>>(le, ce, rowptrL, rowptrC, rankL, rankC,
                                       srcL2C, srcC2L, E);

  init_emb<<<1024, 256, 0, stream>>>(l_emb, l_init, L * 64);
  init_emb<<<1024, 256, 0, stream>>>(c_emb, c_init, C * 64);

  int TL = L >> 4, TC = C >> 4;
  for (int it = 0; it < 8; ++it) {
    mlp_kernel<<<768, 256, 0, stream>>>(l_emb, l_msg, TL, gMl, l2c_b1, l2c_b2,
                                        c_emb, c_msg, TC, gMc, c2l_b1, c2l_b2, 512);
    aggr_kernel<<<2048, 256, 0, stream>>>(l_msg, rowptrC, srcL2C, l2c_aggr, C,
                                          c_msg, rowptrL, srcC2L, c2l_aggr, L);
    gru_kernel<64><<<256, 512, 0, stream>>>(l2c_aggr, c_emb, gGc, gc_bih, gc_bhh, C);
    gru_kernel<128><<<256, 512, 0, stream>>>(c2l_aggr, l_emb, gGl, gl_bih, gl_bhh, L);
  }

  hipMemsetAsync(gsum, 0, 128 * 64 * 4, stream);
  hipMemsetAsync(gcnt, 0, 128 * 4, stream);
  readout_sum<<<512, 256, 0, stream>>>(l_emb, lb, gsum, gcnt, L);
  final_kernel<<<1, 128, 0, stream>>>(gsum, gcnt, ro_W1, ro_b1, ro_W2, ro_b2,
                                      (float*)d_out);
}

// Round 11
// 2440.963 us; speedup vs baseline: 4.2164x; 1.0651x over previous
//
#include <hip/hip_runtime.h>
#include <stdint.h>

// ---------- types / helpers ----------
typedef short bf16x8 __attribute__((ext_vector_type(8)));   // 8 bf16 = 4 VGPR (MFMA A/B frag)
typedef float f32x4  __attribute__((ext_vector_type(4)));   // MFMA C/D frag

__device__ __forceinline__ unsigned short f2bf(float x) {
  unsigned int u = __builtin_bit_cast(unsigned int, x);
  u += 0x7fffu + ((u >> 16) & 1u);
  return (unsigned short)(u >> 16);
}
__device__ __forceinline__ float bf2f(unsigned short b) {
  unsigned int u = ((unsigned int)b) << 16;
  return __builtin_bit_cast(float, u);
}
__device__ __forceinline__ f32x4 mfma16(bf16x8 a, bf16x8 b, f32x4 c) {
  return __builtin_amdgcn_mfma_f32_16x16x32_bf16(a, b, c, 0, 0, 0);
}
// load 8 consecutive f32, split into hi/lo bf16 (hi+lo ~ f32-exact)
__device__ __forceinline__ void split8(const float* __restrict__ p, bf16x8* h, bf16x8* l) {
  float4 a = *reinterpret_cast<const float4*>(p);
  float4 b = *reinterpret_cast<const float4*>(p + 4);
  float v[8] = {a.x, a.y, a.z, a.w, b.x, b.y, b.z, b.w};
  bf16x8 hh, ll;
#pragma unroll
  for (int i = 0; i < 8; ++i) {
    unsigned short hb = f2bf(v[i]);
    hh[i] = (short)hb;
    ll[i] = (short)f2bf(v[i] - bf2f(hb));
  }
  *h = hh; *l = ll;
}
__device__ __forceinline__ float fexp(float x) {  // e^x via v_exp_f32
  return __builtin_amdgcn_exp2f(x * 1.4426950408889634f);
}
__device__ __forceinline__ float sigm(float x) {
  return __builtin_amdgcn_rcpf(1.f + fexp(-x));
}
__device__ __forceinline__ float tanh_fast(float x) {
  x = fminf(fmaxf(x, -15.f), 15.f);
  float e2 = fexp(2.f * x);
  return (e2 - 1.f) * __builtin_amdgcn_rcpf(e2 + 1.f);
}

// ---------- weight prep: split f32 weights into frag-ordered bf16 hi/lo (once) ----------
// gGl layout (ushort): ihH[0,24576) ihL[24576,49152) hhH[49152,61440) hhL[61440,73728)
// gGc layout:          ihH[0,12288) ihL[12288,24576) hhH[24576,36864) hhL[36864,49152)
// gMl/gMc layout:      W1H[0,4096)  W1L[4096,8192)   W2H[8192,12288)  W2L[12288,16384)
__global__ void prep_split(const float* __restrict__ glWih, const float* __restrict__ glWhh,
                           const float* __restrict__ gcWih, const float* __restrict__ gcWhh,
                           const float* __restrict__ mlW1, const float* __restrict__ mlW2,
                           const float* __restrict__ mcW1, const float* __restrict__ mcW2,
                           unsigned short* __restrict__ gGl, unsigned short* __restrict__ gGc,
                           unsigned short* __restrict__ gMl, unsigned short* __restrict__ gMc) {
  int b = blockIdx.x, t = threadIdx.x;
  const float* src; unsigned short *dh, *dl; int NT, KX;
  switch (b) {
    case 0: src = glWih; dh = gGl;         dl = gGl + 24576; NT = 12; KX = 128; break;
    case 1: src = glWhh; dh = gGl + 49152; dl = gGl + 61440; NT = 12; KX = 64;  break;
    case 2: src = gcWih; dh = gGc;         dl = gGc + 12288; NT = 12; KX = 64;  break;
    case 3: src = gcWhh; dh = gGc + 24576; dl = gGc + 36864; NT = 12; KX = 64;  break;
    case 4: src = mlW1;  dh = gMl;         dl = gMl + 4096;  NT = 4;  KX = 64;  break;
    case 5: src = mlW2;  dh = gMl + 8192;  dl = gMl + 12288; NT = 4;  KX = 64;  break;
    case 6: src = mcW1;  dh = gMc;         dl = gMc + 4096;  NT = 4;  KX = 64;  break;
    default: src = mcW2; dh = gMc + 8192;  dl = gMc + 12288; NT = 4;  KX = 64;  break;
  }
  int NKC = KX / 32;
  int tot = NT * NKC * 64;
  for (int e = t; e < tot; e += 256) {
    int f = e >> 6, l = e & 63;
    int nt = f / NKC, kc = f % NKC;
    int n = nt * 16 + (l & 15), k0 = kc * 32 + (l >> 4) * 8;
    bf16x8 h, lo;
    split8(src + n * KX + k0, &h, &lo);
    *reinterpret_cast<bf16x8*>(dh + e * 8) = h;
    *reinterpret_cast<bf16x8*>(dl + e * 8) = lo;
  }
}

// ---------- fused 2x MLP (grid split), operand-swapped MFMA: D = W·X^T ----------
// lane holds one x-row (lane&15) and 4 consecutive n-cols ((lane>>4)*4+i) -> float4 stores.
__global__ __launch_bounds__(256, 3) void mlp_kernel(
    const float* __restrict__ X1, float* __restrict__ Y1, int T1,
    const unsigned short* __restrict__ g1, const float* __restrict__ B11, const float* __restrict__ B21,
    const float* __restrict__ X2, float* __restrict__ Y2, int T2,
    const unsigned short* __restrict__ g2, const float* __restrict__ B12, const float* __restrict__ B22,
    int G1) {
  const float* X; float* Y; int tiles, b, nb;
  const unsigned short* gw; const float *B1, *B2;
  if ((int)blockIdx.x < G1) {
    X = X1; Y = Y1; tiles = T1; gw = g1; B1 = B11; B2 = B21; b = blockIdx.x; nb = G1;
  } else {
    X = X2; Y = Y2; tiles = T2; gw = g2; B1 = B12; B2 = B22; b = blockIdx.x - G1; nb = gridDim.x - G1;
  }
  __shared__ __align__(16) unsigned short wbuf[16384];
  __shared__ __align__(16) float hbuf[4][16 * 68];
  int tid = threadIdx.x, wid = tid >> 6, lane = tid & 63;
  int r = lane & 15, kb = lane >> 4;
  for (int i4 = tid; i4 < 2048; i4 += 256)
    *reinterpret_cast<int4*>(wbuf + i4 * 8) = *reinterpret_cast<const int4*>(gw + i4 * 8);
  __syncthreads();
  const unsigned short *w1h = wbuf, *w1l = wbuf + 4096, *w2h = wbuf + 8192, *w2l = wbuf + 12288;
  f32x4 b1f[4], b2f[4];
#pragma unroll
  for (int nt = 0; nt < 4; ++nt) {
    b1f[nt] = *reinterpret_cast<const f32x4*>(B1 + nt * 16 + kb * 4);
    b2f[nt] = *reinterpret_cast<const f32x4*>(B2 + nt * 16 + kb * 4);
  }
  float* hl = hbuf[wid];
  for (int t = b * 4 + wid; t < tiles; t += nb * 4) {
    int row0 = t << 4;
    const float* xp = X + (size_t)(row0 + r) * 64 + kb * 8;
    bf16x8 a0h, a0l, a1h, a1l;
    split8(xp, &a0h, &a0l);
    split8(xp + 32, &a1h, &a1l);
#pragma unroll
    for (int nt = 0; nt < 4; ++nt) {
      f32x4 c = b1f[nt];
      bf16x8 wh = *reinterpret_cast<const bf16x8*>(w1h + ((nt * 2 + 0) * 64 + lane) * 8);
      bf16x8 wl = *reinterpret_cast<const bf16x8*>(w1l + ((nt * 2 + 0) * 64 + lane) * 8);
      c = mfma16(wh, a0l, c); c = mfma16(wl, a0h, c); c = mfma16(wh, a0h, c);
      wh = *reinterpret_cast<const bf16x8*>(w1h + ((nt * 2 + 1) * 64 + lane) * 8);
      wl = *reinterpret_cast<const bf16x8*>(w1l + ((nt * 2 + 1) * 64 + lane) * 8);
      c = mfma16(wh, a1l, c); c = mfma16(wl, a1h, c); c = mfma16(wh, a1h, c);
#pragma unroll
      for (int i = 0; i < 4; ++i) c[i] = fmaxf(c[i], 0.f);
      *reinterpret_cast<f32x4*>(hl + r * 68 + nt * 16 + kb * 4) = c;  // b128 write, own row
    }
    // same-wave LDS RAW: DS pipe is in-order within a wave
    bf16x8 h0h, h0l, h1h, h1l;
    split8(hl + r * 68 + kb * 8, &h0h, &h0l);
    split8(hl + r * 68 + 32 + kb * 8, &h1h, &h1l);
    float* yp = Y + (size_t)row0 * 64;
#pragma unroll
    for (int nt = 0; nt < 4; ++nt) {
      f32x4 c = b2f[nt];
      bf16x8 wh = *reinterpret_cast<const bf16x8*>(w2h + ((nt * 2 + 0) * 64 + lane) * 8);
      bf16x8 wl = *reinterpret_cast<const bf16x8*>(w2l + ((nt * 2 + 0) * 64 + lane) * 8);
      c = mfma16(wh, h0l, c); c = mfma16(wl, h0h, c); c = mfma16(wh, h0h, c);
      wh = *reinterpret_cast<const bf16x8*>(w2h + ((nt * 2 + 1) * 64 + lane) * 8);
      wl = *reinterpret_cast<const bf16x8*>(w2l + ((nt * 2 + 1) * 64 + lane) * 8);
      c = mfma16(wh, h1l, c); c = mfma16(wl, h1h, c); c = mfma16(wh, h1h, c);
      *reinterpret_cast<f32x4*>(yp + (size_t)r * 64 + nt * 16 + kb * 4) = c;  // float4 store
    }
  }
}

// ---------- GRU body (round-9 structure, verified): hi/lo 3-term, swapped MFMA ----------
// q loop NOT unrolled: keeps live set + scheduler temporaries inside 128 VGPR.
template <int KX>
__device__ __forceinline__ void gru_impl(
    unsigned short* __restrict__ wlds, float* __restrict__ ldsB,
    const float* __restrict__ Xa, float* __restrict__ H,
    const unsigned short* __restrict__ gws,
    const float* __restrict__ Bih, const float* __restrict__ Bhh,
    int M, int bid, int nb) {
  constexpr int NKC_X = KX / 32;
  constexpr int NFX = 12 * NKC_X;
  constexpr int IHL = NFX * 512;       // ihL offset (ushorts)
  constexpr int HH0 = 2 * NFX * 512;   // hhH
  constexpr int HHL = HH0 + 12288;     // hhL
  constexpr int TOTU = HH0 + 24576;
  int tid = threadIdx.x;
  for (int i4 = tid; i4 < TOTU / 8; i4 += 512)
    *reinterpret_cast<int4*>(wlds + i4 * 8) = *reinterpret_cast<const int4*>(gws + i4 * 8);
  if (tid < 128) ldsB[tid] = Bih[tid] + Bhh[tid];
  else if (tid < 192) ldsB[tid] = Bih[tid];            // bnI: Bih[128+j] at ldsB[128+j]
  else if (tid < 256) ldsB[tid] = Bhh[tid - 64];       // bnH: Bhh[128+j] at ldsB[192+j]
  __syncthreads();
  int wid = tid >> 6, lane = tid & 63;
  int r = lane & 15, kb = lane >> 4;
  int tiles = M >> 4;
  for (int t = bid * 8 + wid; t < tiles; t += nb * 8) {
    int row0 = t << 4;
    bf16x8 axh[NKC_X], axl[NKC_X], ahh[2], ahl[2];
#pragma unroll
    for (int kc = 0; kc < 2; ++kc)
      split8(Xa + (size_t)(row0 + r) * 64 + kc * 32 + kb * 8, &axh[kc], &axl[kc]);
    if (KX == 128) {
#pragma unroll
      for (int kc = 0; kc < 2; ++kc)  // pair-flip lives inside this 16-row tile
        split8(H + (size_t)((row0 + r) ^ 1) * 64 + kc * 32 + kb * 8, &axh[2 + kc], &axl[2 + kc]);
    }
#pragma unroll
    for (int kc = 0; kc < 2; ++kc)
      split8(H + (size_t)(row0 + r) * 64 + kc * 32 + kb * 8, &ahh[kc], &ahl[kc]);

    auto dot_ih = [&](int nt) -> f32x4 {
      f32x4 c; c[0] = c[1] = c[2] = c[3] = 0.f;
#pragma unroll
      for (int kc = 0; kc < NKC_X; ++kc) {
        bf16x8 wh = *reinterpret_cast<const bf16x8*>(wlds + (nt * NKC_X + kc) * 512 + lane * 8);
        bf16x8 wl = *reinterpret_cast<const bf16x8*>(wlds + IHL + (nt * NKC_X + kc) * 512 + lane * 8);
        c = mfma16(wh, axl[kc], c);
        c = mfma16(wl, axh[kc], c);
        c = mfma16(wh, axh[kc], c);
      }
      return c;
    };
    auto dot_hh = [&](int nt) -> f32x4 {
      f32x4 c; c[0] = c[1] = c[2] = c[3] = 0.f;
#pragma unroll
      for (int kc = 0; kc < 2; ++kc) {
        bf16x8 wh = *reinterpret_cast<const bf16x8*>(wlds + HH0 + (nt * 2 + kc) * 512 + lane * 8);
        bf16x8 wl = *reinterpret_cast<const bf16x8*>(wlds + HHL + (nt * 2 + kc) * 512 + lane * 8);
        c = mfma16(wh, ahl[kc], c);
        c = mfma16(wl, ahh[kc], c);
        c = mfma16(wh, ahh[kc], c);
      }
      return c;
    };

#pragma unroll 1
    for (int q = 0; q < 4; ++q) {
      f32x4 pr = dot_ih(q);     f32x4 qr = dot_hh(q);
      f32x4 pz = dot_ih(q + 4); f32x4 qz = dot_hh(q + 4);
      f32x4 pn = dot_ih(q + 8); f32x4 qn = dot_hh(q + 8);
      int cb = q * 16 + kb * 4;  // 4 consecutive H columns owned by this lane
      f32x4 bR = *reinterpret_cast<const f32x4*>(ldsB + cb);
      f32x4 bZ = *reinterpret_cast<const f32x4*>(ldsB + 64 + cb);
      f32x4 bI = *reinterpret_cast<const f32x4*>(ldsB + 128 + cb);
      f32x4 bH = *reinterpret_cast<const f32x4*>(ldsB + 192 + cb);
      float* hp = H + (size_t)(row0 + r) * 64 + cb;
      f32x4 hv = *reinterpret_cast<const f32x4*>(hp);
      f32x4 hn;
#pragma unroll
      for (int i = 0; i < 4; ++i) {
        float rg = sigm(pr[i] + qr[i] + bR[i]);
        float zg = sigm(pz[i] + qz[i] + bZ[i]);
        float tn = tanh_fast(pn[i] + bI[i] + rg * (qn[i] + bH[i]));
        hn[i] = (1.f - zg) * tn + zg * hv[i];
      }
      *reinterpret_cast<f32x4*>(hp) = hn;  // aligned float4 store
    }
  }
}

// ---------- fused GRU dispatch: blocks [0,G1) run GRU_c (KX=64), rest GRU_l (KX=128) ----------
// c_emb and l_emb are disjoint -> safe concurrency; work-balanced split keeps CUs full.
__global__ __launch_bounds__(512, 1) void gru_fused(
    const float* __restrict__ XaC, float* __restrict__ HC,
    const unsigned short* __restrict__ gGc,
    const float* __restrict__ BihC, const float* __restrict__ BhhC, int MC, int G1,
    const float* __restrict__ XaL, float* __restrict__ HL,
    const unsigned short* __restrict__ gGl,
    const float* __restrict__ BihL, const float* __restrict__ BhhL, int ML) {
  __shared__ __align__(16) unsigned short wlds[73728];  // max (KX=128) = 147456 B
  __shared__ __align__(16) float ldsB[256];
  if ((int)blockIdx.x < G1)
    gru_impl<64>(wlds, ldsB, XaC, HC, gGc, BihC, BhhC, MC, blockIdx.x, G1);
  else
    gru_impl<128>(wlds, ldsB, XaL, HL, gGl, BihL, BhhL, ML,
                  blockIdx.x - G1, gridDim.x - G1);
}

// ---------- fused 2x CSR gather aggregation, float4 lanes: 4 edges in flight/load ----------
// lane: quarter q=lane>>4 handles edge j+q; cols (lane&15)*4..+3. Cross-quarter shfl reduce.
__global__ __launch_bounds__(256, 4) void aggr_kernel(
    const float* __restrict__ msgA, const int* __restrict__ rpA,
    const int* __restrict__ srcA, float* __restrict__ outA, int NA,
    const float* __restrict__ msgB, const int* __restrict__ rpB,
    const int* __restrict__ srcB, float* __restrict__ outB, int NB) {
  int gtid = blockIdx.x * 256 + threadIdx.x;
  int w = gtid >> 6, lane = gtid & 63;
  int q = lane >> 4, c = (lane & 15) * 4;
  int nw = gridDim.x * 4;
  int tot = NA + NB;
  for (int d = w; d < tot; d += nw) {
    const float* msg; const int* rp; const int* srcv; float* out; int dst;
    if (d < NA) { msg = msgA; rp = rpA; srcv = srcA; out = outA; dst = d; }
    else        { msg = msgB; rp = rpB; srcv = srcB; out = outB; dst = d - NA; }
    int p0 = rp[dst], p1 = rp[dst + 1];
    f32x4 acc0; acc0[0] = acc0[1] = acc0[2] = acc0[3] = 0.f;
    f32x4 acc1; acc1[0] = acc1[1] = acc1[2] = acc1[3] = 0.f;
    int j = p0;
    for (; j + 8 <= p1; j += 8) {
      int s0 = srcv[j + q];
      int s1 = srcv[j + 4 + q];
      float4 v0 = *reinterpret_cast<const float4*>(msg + (size_t)s0 * 64 + c);
      float4 v1 = *reinterpret_cast<const float4*>(msg + (size_t)s1 * 64 + c);
      acc0[0] += v0.x; acc0[1] += v0.y; acc0[2] += v0.z; acc0[3] += v0.w;
      acc1[0] += v1.x; acc1[1] += v1.y; acc1[2] += v1.z; acc1[3] += v1.w;
    }
    if (j + q < p1) {  // tail group 0 (predicated per quarter)
      int s = srcv[j + q];
      float4 v = *reinterpret_cast<const float4*>(msg + (size_t)s * 64 + c);
      acc0[0] += v.x; acc0[1] += v.y; acc0[2] += v.z; acc0[3] += v.w;
    }
    if (j + 4 + q < p1) {  // tail group 1
      int s = srcv[j + 4 + q];
      float4 v = *reinterpret_cast<const float4*>(msg + (size_t)s * 64 + c);
      acc1[0] += v.x; acc1[1] += v.y; acc1[2] += v.z; acc1[3] += v.w;
    }
#pragma unroll
    for (int i = 0; i < 4; ++i) {
      float a = acc0[i] + acc1[i];
      a += __shfl_xor(a, 16, 64);
      a += __shfl_xor(a, 32, 64);
      acc0[i] = a;
    }
    if (q == 0) {
      float4 o; o.x = acc0[0]; o.y = acc0[1]; o.z = acc0[2]; o.w = acc0[3];
      *reinterpret_cast<float4*>(out + (size_t)dst * 64 + c) = o;
    }
  }
}

// ---------- CSR build (rank captured at count time -> atomic-free fill) ----------
__global__ void count_kernel(const int* __restrict__ le, const int* __restrict__ ce,
                             int* __restrict__ degL, int* __restrict__ degC,
                             int* __restrict__ rankL, int* __restrict__ rankC, int E) {
  for (int e = blockIdx.x * 256 + threadIdx.x; e < E; e += gridDim.x * 256) {
    rankL[e] = atomicAdd(&degL[le[e]], 1);
    rankC[e] = atomicAdd(&degC[ce[e]], 1);
  }
}
// fused C+L scans: blocks [0,256) handle array A, [256,512) handle array B
__global__ void scan_pass1(const int* __restrict__ inA, int* __restrict__ bsumA, int NA, int chA,
                           const int* __restrict__ inB, int* __restrict__ bsumB, int NB, int chB) {
  const int* in; int* bsum; int N, chunk, b;
  if ((int)blockIdx.x < 256) { in = inA; bsum = bsumA; N = NA; chunk = chA; b = blockIdx.x; }
  else                       { in = inB; bsum = bsumB; N = NB; chunk = chB; b = blockIdx.x - 256; }
  int t = threadIdx.x;
  int base = b * chunk;
  int seg = (chunk + 255) >> 8;
  int a = base + t * seg;
  int e = min(min(N, base + chunk), a + seg);
  int s = 0;
  for (int i = a; i < e; ++i) s += in[i];
  __shared__ int red[256];
  red[t] = s; __syncthreads();
  for (int off = 128; off > 0; off >>= 1) {
    if (t < off) red[t] += red[t + off];
    __syncthreads();
  }
  if (t == 0) bsum[b] = red[0];
}
__global__ void scan_pass2(int* bsumA, int* totalA, int* bsumB, int* totalB) {
  int* bsum; int* totalOut;
  if (blockIdx.x == 0) { bsum = bsumA; totalOut = totalA; }
  else                 { bsum = bsumB; totalOut = totalB; }
  __shared__ int sc[256];
  int t = threadIdx.x;
  int v = bsum[t];
  sc[t] = v; __syncthreads();
  for (int off = 1; off < 256; off <<= 1) {
    int u = (t >= off) ? sc[t - off] : 0;
    __syncthreads();
    sc[t] += u;
    __syncthreads();
  }
  bsum[t] = sc[t] - v;
  if (t == 255) *totalOut = sc[255];
}
__global__ void scan_pass3(const int* __restrict__ inA, const int* __restrict__ bsumA,
                           int* __restrict__ outA, int NA, int chA,
                           const int* __restrict__ inB, const int* __restrict__ bsumB,
                           int* __restrict__ outB, int NB, int chB) {
  const int *in, *bsum; int* outp; int N, chunk, b;
  if ((int)blockIdx.x < 256) { in = inA; bsum = bsumA; outp = outA; N = NA; chunk = chA; b = blockIdx.x; }
  else                       { in = inB; bsum = bsumB; outp = outB; N = NB; chunk = chB; b = blockIdx.x - 256; }
  int t = threadIdx.x;
  int base = b * chunk;
  int seg = (chunk + 255) >> 8;
  int a = base + t * seg;
  int e = min(min(N, base + chunk), a + seg);
  int s = 0;
  for (int i = a; i < e; ++i) s += in[i];
  __shared__ int sc[256];
  int v = s;
  sc[t] = v; __syncthreads();
  for (int off = 1; off < 256; off <<= 1) {
    int u = (t >= off) ? sc[t - off] : 0;
    __syncthreads();
    sc[t] += u;
    __syncthreads();
  }
  int run = bsum[b] + sc[t] - v;
  for (int i = a; i < e; ++i) { outp[i] = run; run += in[i]; }
}
__global__ void fill_kernel(const int* __restrict__ le, const int* __restrict__ ce,
                            const int* __restrict__ rowptrL, const int* __restrict__ rowptrC,
                            const int* __restrict__ rankL, const int* __restrict__ rankC,
                            int* __restrict__ srcL2C, int* __restrict__ srcC2L, int E) {
  for (int e = blockIdx.x * 256 + threadIdx.x; e < E; e += gridDim.x * 256) {
    int ls = le[e], cd = ce[e];
    srcL2C[rowptrC[cd] + rankC[e]] = ls;
    srcC2L[rowptrL[ls] + rankL[e]] = cd;
  }
}

// ---------- init / readout ----------
__global__ void init_emb2(float* __restrict__ l_emb, float* __restrict__ c_emb,
                          const float* __restrict__ li, const float* __restrict__ ci,
                          int nl, int nc) {
  int tot = nl + nc;
  for (int i = blockIdx.x * 256 + threadIdx.x; i < tot; i += gridDim.x * 256) {
    if (i < nl) l_emb[i] = li[i & 63];
    else        c_emb[i - nl] = ci[(i - nl) & 63];
  }
}
__global__ void readout_sum(const float* __restrict__ lemb, const int* __restrict__ lb,
                            float* __restrict__ gsum, float* __restrict__ gcnt, int L) {
  int gtid = blockIdx.x * 256 + threadIdx.x;
  int w = gtid >> 6, lane = gtid & 63;
  int nw = gridDim.x * 4;
  int chunk = (L + nw - 1) / nw;
  int s = w * chunk, e = min(L, s + chunk);
  if (s >= e) return;
  float acc = 0.f, cnt = 0.f;
  int curb = lb[s];
  for (int row = s; row < e; ++row) {
    int b = lb[row];
    if (b != curb) {
      atomicAdd(&gsum[curb * 64 + lane], acc);
      if (lane == 0) atomicAdd(&gcnt[curb], cnt);
      acc = 0.f; cnt = 0.f; curb = b;
    }
    acc += lemb[(size_t)row * 64 + lane];
    cnt += 1.f;
  }
  atomicAdd(&gsum[curb * 64 + lane], acc);
  if (lane == 0) atomicAdd(&gcnt[curb], cnt);
}
__global__ void final_kernel(const float* __restrict__ gsum, const float* __restrict__ gcnt,
                             const float* __restrict__ W1, const float* __restrict__ B1,
                             const float* __restrict__ W2, const float* __restrict__ B2,
                             float* __restrict__ outp) {
  __shared__ float w1s[4096];
  __shared__ float w2s[64];
  int t = threadIdx.x;  // 128 threads: one per graph
  for (int i = t; i < 4096; i += 128) w1s[i] = W1[i];
  if (t < 64) w2s[t] = W2[t];
  __syncthreads();
  float x[64];
  float c = fmaxf(gcnt[t], 1.f);
#pragma unroll
  for (int d = 0; d < 64; ++d) x[d] = gsum[t * 64 + d] / c;
  float acc = B2[0];
  for (int j = 0; j < 64; ++j) {
    float h = B1[j];
#pragma unroll
    for (int k = 0; k < 64; ++k) h += x[k] * w1s[j * 64 + k];
    acc += fmaxf(h, 0.f) * w2s[j];
  }
  outp[t] = 1.f / (1.f + __expf(-acc));
}

// ---------- launch ----------
extern "C" void kernel_launch(void* const* d_in, const int* in_sizes, int n_in,
                              void* d_out, int out_size, void* d_ws, size_t ws_size,
                              hipStream_t stream) {
  const int* le = (const int*)d_in[2];
  const int* ce = (const int*)d_in[3];
  const int* lb = (const int*)d_in[4];
  const float* l_init = (const float*)d_in[5];
  const float* c_init = (const float*)d_in[6];
  const float* l2c_W1 = (const float*)d_in[7];
  const float* l2c_b1 = (const float*)d_in[8];
  const float* l2c_W2 = (const float*)d_in[9];
  const float* l2c_b2 = (const float*)d_in[10];
  const float* c2l_W1 = (const float*)d_in[11];
  const float* c2l_b1 = (const float*)d_in[12];
  const float* c2l_W2 = (const float*)d_in[13];
  const float* c2l_b2 = (const float*)d_in[14];
  const float* gc_Wih = (const float*)d_in[15];
  const float* gc_Whh = (const float*)d_in[16];
  const float* gc_bih = (const float*)d_in[17];
  const float* gc_bhh = (const float*)d_in[18];
  const float* gl_Wih = (const float*)d_in[19];
  const float* gl_Whh = (const float*)d_in[20];
  const float* gl_bih = (const float*)d_in[21];
  const float* gl_bhh = (const float*)d_in[22];
  const float* ro_W1 = (const float*)d_in[23];
  const float* ro_b1 = (const float*)d_in[24];
  const float* ro_W2 = (const float*)d_in[25];
  const float* ro_b2 = (const float*)d_in[26];
  const int E = in_sizes[2];
  const int L = in_sizes[4];
  const int C = 100000;

  char* p = (char*)d_ws;
  auto alloc = [&](size_t b) -> char* {
    char* r = p;
    p += (b + 255) & ~(size_t)255;
    return r;
  };
  float* l_emb = (float*)alloc((size_t)L * 64 * 4);
  float* c_emb = (float*)alloc((size_t)C * 64 * 4);
  float* l_msg = (float*)alloc((size_t)L * 64 * 4);
  float* c_msg = (float*)alloc((size_t)C * 64 * 4);
  float* l2c_aggr = (float*)alloc((size_t)C * 64 * 4);
  float* c2l_aggr = (float*)alloc((size_t)L * 64 * 4);
  int* rowptrC = (int*)alloc((size_t)(C + 1) * 4);
  int* rowptrL = (int*)alloc((size_t)(L + 1) * 4);
  int* degC = (int*)alloc((size_t)C * 4);
  int* degL = (int*)alloc((size_t)L * 4);
  int* srcL2C = (int*)alloc((size_t)E * 4);
  int* srcC2L = (int*)alloc((size_t)E * 4);
  int* rankL = (int*)alloc((size_t)E * 4);
  int* rankC = (int*)alloc((size_t)E * 4);
  int* bsum = (int*)alloc(512 * 4);  // [0,256) C, [256,512) L
  float* gsum = (float*)alloc(128 * 64 * 4);
  float* gcnt = (float*)alloc(128 * 4);
  unsigned short* gGl = (unsigned short*)alloc(73728 * 2);
  unsigned short* gGc = (unsigned short*)alloc(49152 * 2);
  unsigned short* gMl = (unsigned short*)alloc(16384 * 2);
  unsigned short* gMc = (unsigned short*)alloc(16384 * 2);

  // weight prep (once per launch)
  prep_split<<<8, 256, 0, stream>>>(gl_Wih, gl_Whh, gc_Wih, gc_Whh,
                                    l2c_W1, l2c_W2, c2l_W1, c2l_W2,
                                    gGl, gGc, gMl, gMc);

  // CSR build (once per launch; reused by all 16 aggregations)
  hipMemsetAsync(degC, 0, (size_t)C * 4, stream);
  hipMemsetAsync(degL, 0, (size_t)L * 4, stream);
  count_kernel<<<512, 256, 0, stream>>>(le, ce, degL, degC, rankL, rankC, E);
  int chC = (C + 255) / 256, chL = (L + 255) / 256;
  scan_pass1<<<512, 256, 0, stream>>>(degC, bsum, C, chC, degL, bsum + 256, L, chL);
  scan_pass2<<<2, 256, 0, stream>>>(bsum, rowptrC + C, bsum + 256, rowptrL + L);
  scan_pass3<<<512, 256, 0, stream>>>(degC, bsum, rowptrC, C, chC,
                                      degL, bsum + 256, rowptrL, L, chL);
  fill_kernel<<<512, 256, 0, stream>>>(le, ce, rowptrL, rowptrC, rankL, rankC,
                                       srcL2C, srcC2L, E);

  init_emb2<<<1024, 256, 0, stream>>>(l_emb, c_emb, l_init, c_init, L * 64, C * 64);

  int TL = L >> 4, TC = C >> 4;
  for (int it = 0; it < 8; ++it) {
    mlp_kernel<<<768, 256, 0, stream>>>(l_emb, l_msg, TL, gMl, l2c_b1, l2c_b2,
                                        c_emb, c_msg, TC, gMc, c2l_b1, c2l_b2, 512);
    aggr_kernel<<<2048, 256, 0, stream>>>(l_msg, rowptrC, srcL2C, l2c_aggr, C,
                                          c_msg, rowptrL, srcC2L, c2l_aggr, L);
    gru_fused<<<256, 512, 0, stream>>>(l2c_aggr, c_emb, gGc, gc_bih, gc_bhh, C, 64,
                                       c2l_aggr, l_emb, gGl, gl_bih, gl_bhh, L);
  }

  hipMemsetAsync(gsum, 0, 128 * 64 * 4, stream);
  hipMemsetAsync(gcnt, 0, 128 * 4, stream);
  readout_sum<<<512, 256, 0, stream>>>(l_emb, lb, gsum, gcnt, L);
  final_kernel<<<1, 128, 0, stream>>>(gsum, gcnt, ro_W1, ro_b1, ro_W2, ro_b2,
                                      (float*)d_out);
}

// Round 12
// 2261.666 us; speedup vs baseline: 4.5506x; 1.0793x over previous
//
#include <hip/hip_runtime.h>
#include <stdint.h>

// ---------- types / helpers ----------
typedef short bf16x8 __attribute__((ext_vector_type(8)));   // 8 bf16 = 4 VGPR (MFMA A/B frag)
typedef float f32x4  __attribute__((ext_vector_type(4)));   // MFMA C/D frag

__device__ __forceinline__ unsigned short f2bf(float x) {
  unsigned int u = __builtin_bit_cast(unsigned int, x);
  u += 0x7fffu + ((u >> 16) & 1u);
  return (unsigned short)(u >> 16);
}
__device__ __forceinline__ float bf2f(unsigned short b) {
  unsigned int u = ((unsigned int)b) << 16;
  return __builtin_bit_cast(float, u);
}
__device__ __forceinline__ f32x4 mfma16(bf16x8 a, bf16x8 b, f32x4 c) {
  return __builtin_amdgcn_mfma_f32_16x16x32_bf16(a, b, c, 0, 0, 0);
}
// load 8 consecutive f32, split into hi/lo bf16 (hi+lo ~ f32-exact)
__device__ __forceinline__ void split8(const float* __restrict__ p, bf16x8* h, bf16x8* l) {
  float4 a = *reinterpret_cast<const float4*>(p);
  float4 b = *reinterpret_cast<const float4*>(p + 4);
  float v[8] = {a.x, a.y, a.z, a.w, b.x, b.y, b.z, b.w};
  bf16x8 hh, ll;
#pragma unroll
  for (int i = 0; i < 8; ++i) {
    unsigned short hb = f2bf(v[i]);
    hh[i] = (short)hb;
    ll[i] = (short)f2bf(v[i] - bf2f(hb));
  }
  *h = hh; *l = ll;
}
__device__ __forceinline__ float fexp(float x) {  // e^x via v_exp_f32
  return __builtin_amdgcn_exp2f(x * 1.4426950408889634f);
}
__device__ __forceinline__ float sigm(float x) {
  return __builtin_amdgcn_rcpf(1.f + fexp(-x));
}
__device__ __forceinline__ float tanh_fast(float x) {
  x = fminf(fmaxf(x, -15.f), 15.f);
  float e2 = fexp(2.f * x);
  return (e2 - 1.f) * __builtin_amdgcn_rcpf(e2 + 1.f);
}

// ---------- weight prep: split f32 weights into frag-ordered bf16 hi/lo (once) ----------
// gGl layout (ushort): ihH[0,24576) ihL[24576,49152) hhH[49152,61440) hhL[61440,73728)
// gGc layout:          ihH[0,12288) ihL[12288,24576) hhH[24576,36864) hhL[36864,49152)
// gMl/gMc layout:      W1H[0,4096)  W1L[4096,8192)   W2H[8192,12288)  W2L[12288,16384)
__global__ void prep_split(const float* __restrict__ glWih, const float* __restrict__ glWhh,
                           const float* __restrict__ gcWih, const float* __restrict__ gcWhh,
                           const float* __restrict__ mlW1, const float* __restrict__ mlW2,
                           const float* __restrict__ mcW1, const float* __restrict__ mcW2,
                           unsigned short* __restrict__ gGl, unsigned short* __restrict__ gGc,
                           unsigned short* __restrict__ gMl, unsigned short* __restrict__ gMc) {
  int b = blockIdx.x, t = threadIdx.x;
  const float* src; unsigned short *dh, *dl; int NT, KX;
  switch (b) {
    case 0: src = glWih; dh = gGl;         dl = gGl + 24576; NT = 12; KX = 128; break;
    case 1: src = glWhh; dh = gGl + 49152; dl = gGl + 61440; NT = 12; KX = 64;  break;
    case 2: src = gcWih; dh = gGc;         dl = gGc + 12288; NT = 12; KX = 64;  break;
    case 3: src = gcWhh; dh = gGc + 24576; dl = gGc + 36864; NT = 12; KX = 64;  break;
    case 4: src = mlW1;  dh = gMl;         dl = gMl + 4096;  NT = 4;  KX = 64;  break;
    case 5: src = mlW2;  dh = gMl + 8192;  dl = gMl + 12288; NT = 4;  KX = 64;  break;
    case 6: src = mcW1;  dh = gMc;         dl = gMc + 4096;  NT = 4;  KX = 64;  break;
    default: src = mcW2; dh = gMc + 8192;  dl = gMc + 12288; NT = 4;  KX = 64;  break;
  }
  int NKC = KX / 32;
  int tot = NT * NKC * 64;
  for (int e = t; e < tot; e += 256) {
    int f = e >> 6, l = e & 63;
    int nt = f / NKC, kc = f % NKC;
    int n = nt * 16 + (l & 15), k0 = kc * 32 + (l >> 4) * 8;
    bf16x8 h, lo;
    split8(src + n * KX + k0, &h, &lo);
    *reinterpret_cast<bf16x8*>(dh + e * 8) = h;
    *reinterpret_cast<bf16x8*>(dl + e * 8) = lo;
  }
}

// ---------- fused 2x MLP (grid split), operand-swapped MFMA: D = W·X^T ----------
// lane holds one x-row (lane&15) and 4 consecutive n-cols ((lane>>4)*4+i) -> float4 stores.
__global__ __launch_bounds__(256, 3) void mlp_kernel(
    const float* __restrict__ X1, float* __restrict__ Y1, int T1,
    const unsigned short* __restrict__ g1, const float* __restrict__ B11, const float* __restrict__ B21,
    const float* __restrict__ X2, float* __restrict__ Y2, int T2,
    const unsigned short* __restrict__ g2, const float* __restrict__ B12, const float* __restrict__ B22,
    int G1) {
  const float* X; float* Y; int tiles, b, nb;
  const unsigned short* gw; const float *B1, *B2;
  if ((int)blockIdx.x < G1) {
    X = X1; Y = Y1; tiles = T1; gw = g1; B1 = B11; B2 = B21; b = blockIdx.x; nb = G1;
  } else {
    X = X2; Y = Y2; tiles = T2; gw = g2; B1 = B12; B2 = B22; b = blockIdx.x - G1; nb = gridDim.x - G1;
  }
  __shared__ __align__(16) unsigned short wbuf[16384];
  __shared__ __align__(16) float hbuf[4][16 * 68];
  int tid = threadIdx.x, wid = tid >> 6, lane = tid & 63;
  int r = lane & 15, kb = lane >> 4;
  for (int i4 = tid; i4 < 2048; i4 += 256)
    *reinterpret_cast<int4*>(wbuf + i4 * 8) = *reinterpret_cast<const int4*>(gw + i4 * 8);
  __syncthreads();
  const unsigned short *w1h = wbuf, *w1l = wbuf + 4096, *w2h = wbuf + 8192, *w2l = wbuf + 12288;
  f32x4 b1f[4], b2f[4];
#pragma unroll
  for (int nt = 0; nt < 4; ++nt) {
    b1f[nt] = *reinterpret_cast<const f32x4*>(B1 + nt * 16 + kb * 4);
    b2f[nt] = *reinterpret_cast<const f32x4*>(B2 + nt * 16 + kb * 4);
  }
  float* hl = hbuf[wid];
  for (int t = b * 4 + wid; t < tiles; t += nb * 4) {
    int row0 = t << 4;
    const float* xp = X + (size_t)(row0 + r) * 64 + kb * 8;
    bf16x8 a0h, a0l, a1h, a1l;
    split8(xp, &a0h, &a0l);
    split8(xp + 32, &a1h, &a1l);
#pragma unroll
    for (int nt = 0; nt < 4; ++nt) {
      f32x4 c = b1f[nt];
      bf16x8 wh = *reinterpret_cast<const bf16x8*>(w1h + ((nt * 2 + 0) * 64 + lane) * 8);
      bf16x8 wl = *reinterpret_cast<const bf16x8*>(w1l + ((nt * 2 + 0) * 64 + lane) * 8);
      c = mfma16(wh, a0l, c); c = mfma16(wl, a0h, c); c = mfma16(wh, a0h, c);
      wh = *reinterpret_cast<const bf16x8*>(w1h + ((nt * 2 + 1) * 64 + lane) * 8);
      wl = *reinterpret_cast<const bf16x8*>(w1l + ((nt * 2 + 1) * 64 + lane) * 8);
      c = mfma16(wh, a1l, c); c = mfma16(wl, a1h, c); c = mfma16(wh, a1h, c);
#pragma unroll
      for (int i = 0; i < 4; ++i) c[i] = fmaxf(c[i], 0.f);
      *reinterpret_cast<f32x4*>(hl + r * 68 + nt * 16 + kb * 4) = c;  // b128 write, own row
    }
    // same-wave LDS RAW: DS pipe is in-order within a wave
    bf16x8 h0h, h0l, h1h, h1l;
    split8(hl + r * 68 + kb * 8, &h0h, &h0l);
    split8(hl + r * 68 + 32 + kb * 8, &h1h, &h1l);
    float* yp = Y + (size_t)row0 * 64;
#pragma unroll
    for (int nt = 0; nt < 4; ++nt) {
      f32x4 c = b2f[nt];
      bf16x8 wh = *reinterpret_cast<const bf16x8*>(w2h + ((nt * 2 + 0) * 64 + lane) * 8);
      bf16x8 wl = *reinterpret_cast<const bf16x8*>(w2l + ((nt * 2 + 0) * 64 + lane) * 8);
      c = mfma16(wh, h0l, c); c = mfma16(wl, h0h, c); c = mfma16(wh, h0h, c);
      wh = *reinterpret_cast<const bf16x8*>(w2h + ((nt * 2 + 1) * 64 + lane) * 8);
      wl = *reinterpret_cast<const bf16x8*>(w2l + ((nt * 2 + 1) * 64 + lane) * 8);
      c = mfma16(wh, h1l, c); c = mfma16(wl, h1h, c); c = mfma16(wh, h1h, c);
      *reinterpret_cast<f32x4*>(yp + (size_t)r * 64 + nt * 16 + kb * 4) = c;  // float4 store
    }
  }
}

// ---------- GRU body (round-9 structure, verified): hi/lo 3-term, swapped MFMA ----------
// q loop NOT unrolled: keeps live set + scheduler temporaries inside 128 VGPR.
template <int KX>
__device__ __forceinline__ void gru_impl(
    unsigned short* __restrict__ wlds, float* __restrict__ ldsB,
    const float* __restrict__ Xa, float* __restrict__ H,
    const unsigned short* __restrict__ gws,
    const float* __restrict__ Bih, const float* __restrict__ Bhh,
    int M, int bid, int nb) {
  constexpr int NKC_X = KX / 32;
  constexpr int NFX = 12 * NKC_X;
  constexpr int IHL = NFX * 512;       // ihL offset (ushorts)
  constexpr int HH0 = 2 * NFX * 512;   // hhH
  constexpr int HHL = HH0 + 12288;     // hhL
  constexpr int TOTU = HH0 + 24576;
  int tid = threadIdx.x;
  for (int i4 = tid; i4 < TOTU / 8; i4 += 512)
    *reinterpret_cast<int4*>(wlds + i4 * 8) = *reinterpret_cast<const int4*>(gws + i4 * 8);
  if (tid < 128) ldsB[tid] = Bih[tid] + Bhh[tid];
  else if (tid < 192) ldsB[tid] = Bih[tid];            // bnI: Bih[128+j] at ldsB[128+j]
  else if (tid < 256) ldsB[tid] = Bhh[tid - 64];       // bnH: Bhh[128+j] at ldsB[192+j]
  __syncthreads();
  int wid = tid >> 6, lane = tid & 63;
  int r = lane & 15, kb = lane >> 4;
  int tiles = M >> 4;
  for (int t = bid * 8 + wid; t < tiles; t += nb * 8) {
    int row0 = t << 4;
    bf16x8 axh[NKC_X], axl[NKC_X], ahh[2], ahl[2];
#pragma unroll
    for (int kc = 0; kc < 2; ++kc)
      split8(Xa + (size_t)(row0 + r) * 64 + kc * 32 + kb * 8, &axh[kc], &axl[kc]);
    if (KX == 128) {
#pragma unroll
      for (int kc = 0; kc < 2; ++kc)  // pair-flip lives inside this 16-row tile
        split8(H + (size_t)((row0 + r) ^ 1) * 64 + kc * 32 + kb * 8, &axh[2 + kc], &axl[2 + kc]);
    }
#pragma unroll
    for (int kc = 0; kc < 2; ++kc)
      split8(H + (size_t)(row0 + r) * 64 + kc * 32 + kb * 8, &ahh[kc], &ahl[kc]);

    auto dot_ih = [&](int nt) -> f32x4 {
      f32x4 c; c[0] = c[1] = c[2] = c[3] = 0.f;
#pragma unroll
      for (int kc = 0; kc < NKC_X; ++kc) {
        bf16x8 wh = *reinterpret_cast<const bf16x8*>(wlds + (nt * NKC_X + kc) * 512 + lane * 8);
        bf16x8 wl = *reinterpret_cast<const bf16x8*>(wlds + IHL + (nt * NKC_X + kc) * 512 + lane * 8);
        c = mfma16(wh, axl[kc], c);
        c = mfma16(wl, axh[kc], c);
        c = mfma16(wh, axh[kc], c);
      }
      return c;
    };
    auto dot_hh = [&](int nt) -> f32x4 {
      f32x4 c; c[0] = c[1] = c[2] = c[3] = 0.f;
#pragma unroll
      for (int kc = 0; kc < 2; ++kc) {
        bf16x8 wh = *reinterpret_cast<const bf16x8*>(wlds + HH0 + (nt * 2 + kc) * 512 + lane * 8);
        bf16x8 wl = *reinterpret_cast<const bf16x8*>(wlds + HHL + (nt * 2 + kc) * 512 + lane * 8);
        c = mfma16(wh, ahl[kc], c);
        c = mfma16(wl, ahh[kc], c);
        c = mfma16(wh, ahh[kc], c);
      }
      return c;
    };

#pragma unroll 1
    for (int q = 0; q < 4; ++q) {
      f32x4 pr = dot_ih(q);     f32x4 qr = dot_hh(q);
      f32x4 pz = dot_ih(q + 4); f32x4 qz = dot_hh(q + 4);
      f32x4 pn = dot_ih(q + 8); f32x4 qn = dot_hh(q + 8);
      int cb = q * 16 + kb * 4;  // 4 consecutive H columns owned by this lane
      f32x4 bR = *reinterpret_cast<const f32x4*>(ldsB + cb);
      f32x4 bZ = *reinterpret_cast<const f32x4*>(ldsB + 64 + cb);
      f32x4 bI = *reinterpret_cast<const f32x4*>(ldsB + 128 + cb);
      f32x4 bH = *reinterpret_cast<const f32x4*>(ldsB + 192 + cb);
      float* hp = H + (size_t)(row0 + r) * 64 + cb;
      f32x4 hv = *reinterpret_cast<const f32x4*>(hp);
      f32x4 hn;
#pragma unroll
      for (int i = 0; i < 4; ++i) {
        float rg = sigm(pr[i] + qr[i] + bR[i]);
        float zg = sigm(pz[i] + qz[i] + bZ[i]);
        float tn = tanh_fast(pn[i] + bI[i] + rg * (qn[i] + bH[i]));
        hn[i] = (1.f - zg) * tn + zg * hv[i];
      }
      *reinterpret_cast<f32x4*>(hp) = hn;  // aligned float4 store
    }
  }
}

// ---------- fused GRU dispatch: blocks [0,G1) run GRU_c (KX=64), rest GRU_l (KX=128) ----------
// c_emb and l_emb are disjoint -> safe concurrency; work-balanced split keeps CUs full.
__global__ __launch_bounds__(512, 1) void gru_fused(
    const float* __restrict__ XaC, float* __restrict__ HC,
    const unsigned short* __restrict__ gGc,
    const float* __restrict__ BihC, const float* __restrict__ BhhC, int MC, int G1,
    const float* __restrict__ XaL, float* __restrict__ HL,
    const unsigned short* __restrict__ gGl,
    const float* __restrict__ BihL, const float* __restrict__ BhhL, int ML) {
  __shared__ __align__(16) unsigned short wlds[73728];  // max (KX=128) = 147456 B
  __shared__ __align__(16) float ldsB[256];
  if ((int)blockIdx.x < G1)
    gru_impl<64>(wlds, ldsB, XaC, HC, gGc, BihC, BhhC, MC, blockIdx.x, G1);
  else
    gru_impl<128>(wlds, ldsB, XaL, HL, gGl, BihL, BhhL, ML,
                  blockIdx.x - G1, gridDim.x - G1);
}

// ---------- fused 2x CSR gather aggregation, float4 lanes: 4 edges in flight/load ----------
// lane: quarter q=lane>>4 handles edge j+q; cols (lane&15)*4..+3. Cross-quarter shfl reduce.
__global__ __launch_bounds__(256, 4) void aggr_kernel(
    const float* __restrict__ msgA, const int* __restrict__ rpA,
    const int* __restrict__ srcA, float* __restrict__ outA, int NA,
    const float* __restrict__ msgB, const int* __restrict__ rpB,
    const int* __restrict__ srcB, float* __restrict__ outB, int NB) {
  int gtid = blockIdx.x * 256 + threadIdx.x;
  int w = gtid >> 6, lane = gtid & 63;
  int q = lane >> 4, c = (lane & 15) * 4;
  int nw = gridDim.x * 4;
  int tot = NA + NB;
  for (int d = w; d < tot; d += nw) {
    const float* msg; const int* rp; const int* srcv; float* out; int dst;
    if (d < NA) { msg = msgA; rp = rpA; srcv = srcA; out = outA; dst = d; }
    else        { msg = msgB; rp = rpB; srcv = srcB; out = outB; dst = d - NA; }
    int p0 = rp[dst], p1 = rp[dst + 1];
    f32x4 acc0; acc0[0] = acc0[1] = acc0[2] = acc0[3] = 0.f;
    f32x4 acc1; acc1[0] = acc1[1] = acc1[2] = acc1[3] = 0.f;
    int j = p0;
    for (; j + 8 <= p1; j += 8) {
      int s0 = srcv[j + q];
      int s1 = srcv[j + 4 + q];
      float4 v0 = *reinterpret_cast<const float4*>(msg + (size_t)s0 * 64 + c);
      float4 v1 = *reinterpret_cast<const float4*>(msg + (size_t)s1 * 64 + c);
      acc0[0] += v0.x; acc0[1] += v0.y; acc0[2] += v0.z; acc0[3] += v0.w;
      acc1[0] += v1.x; acc1[1] += v1.y; acc1[2] += v1.z; acc1[3] += v1.w;
    }
    if (j + q < p1) {  // tail group 0 (predicated per quarter)
      int s = srcv[j + q];
      float4 v = *reinterpret_cast<const float4*>(msg + (size_t)s * 64 + c);
      acc0[0] += v.x; acc0[1] += v.y; acc0[2] += v.z; acc0[3] += v.w;
    }
    if (j + 4 + q < p1) {  // tail group 1
      int s = srcv[j + 4 + q];
      float4 v = *reinterpret_cast<const float4*>(msg + (size_t)s * 64 + c);
      acc1[0] += v.x; acc1[1] += v.y; acc1[2] += v.z; acc1[3] += v.w;
    }
#pragma unroll
    for (int i = 0; i < 4; ++i) {
      float a = acc0[i] + acc1[i];
      a += __shfl_xor(a, 16, 64);
      a += __shfl_xor(a, 32, 64);
      acc0[i] = a;
    }
    if (q == 0) {
      float4 o; o.x = acc0[0]; o.y = acc0[1]; o.z = acc0[2]; o.w = acc0[3];
      *reinterpret_cast<float4*>(out + (size_t)dst * 64 + c) = o;
    }
  }
}

// ---------- iteration-0 shortcut: all rows identical -> aggr = deg * MLP(init) ----------
__global__ void msg0_kernel(const float* __restrict__ li, const float* __restrict__ ci,
                            const float* __restrict__ mlW1, const float* __restrict__ mlB1,
                            const float* __restrict__ mlW2, const float* __restrict__ mlB2,
                            const float* __restrict__ mcW1, const float* __restrict__ mcB1,
                            const float* __restrict__ mcW2, const float* __restrict__ mcB2,
                            float* __restrict__ msgL0, float* __restrict__ msgC0) {
  __shared__ float hL[64], hC[64];
  int t = threadIdx.x;  // 128 threads: t<64 l-side, else c-side
  if (t < 64) {
    float h = mlB1[t];
    for (int k = 0; k < 64; ++k) h += li[k] * mlW1[t * 64 + k];
    hL[t] = fmaxf(h, 0.f);
  } else {
    int j = t - 64;
    float h = mcB1[j];
    for (int k = 0; k < 64; ++k) h += ci[k] * mcW1[j * 64 + k];
    hC[j] = fmaxf(h, 0.f);
  }
  __syncthreads();
  if (t < 64) {
    float y = mlB2[t];
    for (int j = 0; j < 64; ++j) y += hL[j] * mlW2[t * 64 + j];
    msgL0[t] = y;
  } else {
    int n = t - 64;
    float y = mcB2[n];
    for (int j = 0; j < 64; ++j) y += hC[j] * mcW2[n * 64 + j];
    msgC0[n] = y;
  }
}
__global__ __launch_bounds__(256) void aggr0_kernel(
    const int* __restrict__ degC, const int* __restrict__ degL,
    const float* __restrict__ msgL0, const float* __restrict__ msgC0,
    float* __restrict__ l2c, float* __restrict__ c2l, int C, int L) {
  __shared__ __align__(16) float sL[64], sC[64];
  if (threadIdx.x < 64) sL[threadIdx.x] = msgL0[threadIdx.x];
  else if (threadIdx.x < 128) sC[threadIdx.x - 64] = msgC0[threadIdx.x - 64];
  __syncthreads();
  int totC = C * 16, totL = L * 16;
  for (int i = blockIdx.x * 256 + threadIdx.x; i < totC + totL; i += gridDim.x * 256) {
    if (i < totC) {
      int node = i >> 4, g = (i & 15) * 4;
      float d = (float)degC[node];
      float4 m = *reinterpret_cast<const float4*>(sL + g);
      float4 o; o.x = d * m.x; o.y = d * m.y; o.z = d * m.z; o.w = d * m.w;
      *reinterpret_cast<float4*>(l2c + (size_t)node * 64 + g) = o;
    } else {
      int ii = i - totC;
      int node = ii >> 4, g = (ii & 15) * 4;
      float d = (float)degL[node];
      float4 m = *reinterpret_cast<const float4*>(sC + g);
      float4 o; o.x = d * m.x; o.y = d * m.y; o.z = d * m.z; o.w = d * m.w;
      *reinterpret_cast<float4*>(c2l + (size_t)node * 64 + g) = o;
    }
  }
}

// ---------- CSR build (rank captured at count time -> atomic-free fill) ----------
__global__ void count_kernel(const int* __restrict__ le, const int* __restrict__ ce,
                             int* __restrict__ degL, int* __restrict__ degC,
                             int* __restrict__ rankL, int* __restrict__ rankC, int E) {
  for (int e = blockIdx.x * 256 + threadIdx.x; e < E; e += gridDim.x * 256) {
    rankL[e] = atomicAdd(&degL[le[e]], 1);
    rankC[e] = atomicAdd(&degC[ce[e]], 1);
  }
}
// fused C+L scans: blocks [0,256) handle array A, [256,512) handle array B
__global__ void scan_pass1(const int* __restrict__ inA, int* __restrict__ bsumA, int NA, int chA,
                           const int* __restrict__ inB, int* __restrict__ bsumB, int NB, int chB) {
  const int* in; int* bsum; int N, chunk, b;
  if ((int)blockIdx.x < 256) { in = inA; bsum = bsumA; N = NA; chunk = chA; b = blockIdx.x; }
  else                       { in = inB; bsum = bsumB; N = NB; chunk = chB; b = blockIdx.x - 256; }
  int t = threadIdx.x;
  int base = b * chunk;
  int seg = (chunk + 255) >> 8;
  int a = base + t * seg;
  int e = min(min(N, base + chunk), a + seg);
  int s = 0;
  for (int i = a; i < e; ++i) s += in[i];
  __shared__ int red[256];
  red[t] = s; __syncthreads();
  for (int off = 128; off > 0; off >>= 1) {
    if (t < off) red[t] += red[t + off];
    __syncthreads();
  }
  if (t == 0) bsum[b] = red[0];
}
__global__ void scan_pass2(int* bsumA, int* totalA, int* bsumB, int* totalB) {
  int* bsum; int* totalOut;
  if (blockIdx.x == 0) { bsum = bsumA; totalOut = totalA; }
  else                 { bsum = bsumB; totalOut = totalB; }
  __shared__ int sc[256];
  int t = threadIdx.x;
  int v = bsum[t];
  sc[t] = v; __syncthreads();
  for (int off = 1; off < 256; off <<= 1) {
    int u = (t >= off) ? sc[t - off] : 0;
    __syncthreads();
    sc[t] += u;
    __syncthreads();
  }
  bsum[t] = sc[t] - v;
  if (t == 255) *totalOut = sc[255];
}
__global__ void scan_pass3(const int* __restrict__ inA, const int* __restrict__ bsumA,
                           int* __restrict__ outA, int NA, int chA,
                           const int* __restrict__ inB, const int* __restrict__ bsumB,
                           int* __restrict__ outB, int NB, int chB) {
  const int *in, *bsum; int* outp; int N, chunk, b;
  if ((int)blockIdx.x < 256) { in = inA; bsum = bsumA; outp = outA; N = NA; chunk = chA; b = blockIdx.x; }
  else                       { in = inB; bsum = bsumB; outp = outB; N = NB; chunk = chB; b = blockIdx.x - 256; }
  int t = threadIdx.x;
  int base = b * chunk;
  int seg = (chunk + 255) >> 8;
  int a = base + t * seg;
  int e = min(min(N, base + chunk), a + seg);
  int s = 0;
  for (int i = a; i < e; ++i) s += in[i];
  __shared__ int sc[256];
  int v = s;
  sc[t] = v; __syncthreads();
  for (int off = 1; off < 256; off <<= 1) {
    int u = (t >= off) ? sc[t - off] : 0;
    __syncthreads();
    sc[t] += u;
    __syncthreads();
  }
  int run = bsum[b] + sc[t] - v;
  for (int i = a; i < e; ++i) { outp[i] = run; run += in[i]; }
}
__global__ void fill_kernel(const int* __restrict__ le, const int* __restrict__ ce,
                            const int* __restrict__ rowptrL, const int* __restrict__ rowptrC,
                            const int* __restrict__ rankL, const int* __restrict__ rankC,
                            int* __restrict__ srcL2C, int* __restrict__ srcC2L, int E) {
  for (int e = blockIdx.x * 256 + threadIdx.x; e < E; e += gridDim.x * 256) {
    int ls = le[e], cd = ce[e];
    srcL2C[rowptrC[cd] + rankC[e]] = ls;
    srcC2L[rowptrL[ls] + rankL[e]] = cd;
  }
}

// ---------- init / readout ----------
__global__ void init_emb2(float* __restrict__ l_emb, float* __restrict__ c_emb,
                          const float* __restrict__ li, const float* __restrict__ ci,
                          int nl, int nc) {
  int tot = nl + nc;
  for (int i = blockIdx.x * 256 + threadIdx.x; i < tot; i += gridDim.x * 256) {
    if (i < nl) l_emb[i] = li[i & 63];
    else        c_emb[i - nl] = ci[(i - nl) & 63];
  }
}
__global__ void readout_sum(const float* __restrict__ lemb, const int* __restrict__ lb,
                            float* __restrict__ gsum, float* __restrict__ gcnt, int L) {
  int gtid = blockIdx.x * 256 + threadIdx.x;
  int w = gtid >> 6, lane = gtid & 63;
  int nw = gridDim.x * 4;
  int chunk = (L + nw - 1) / nw;
  int s = w * chunk, e = min(L, s + chunk);
  if (s >= e) return;
  float acc = 0.f, cnt = 0.f;
  int curb = lb[s];
  for (int row = s; row < e; ++row) {
    int b = lb[row];
    if (b != curb) {
      atomicAdd(&gsum[curb * 64 + lane], acc);
      if (lane == 0) atomicAdd(&gcnt[curb], cnt);
      acc = 0.f; cnt = 0.f; curb = b;
    }
    acc += lemb[(size_t)row * 64 + lane];
    cnt += 1.f;
  }
  atomicAdd(&gsum[curb * 64 + lane], acc);
  if (lane == 0) atomicAdd(&gcnt[curb], cnt);
}
__global__ void final_kernel(const float* __restrict__ gsum, const float* __restrict__ gcnt,
                             const float* __restrict__ W1, const float* __restrict__ B1,
                             const float* __restrict__ W2, const float* __restrict__ B2,
                             float* __restrict__ outp) {
  __shared__ float w1s[4096];
  __shared__ float w2s[64];
  int t = threadIdx.x;  // 128 threads: one per graph
  for (int i = t; i < 4096; i += 128) w1s[i] = W1[i];
  if (t < 64) w2s[t] = W2[t];
  __syncthreads();
  float x[64];
  float c = fmaxf(gcnt[t], 1.f);
#pragma unroll
  for (int d = 0; d < 64; ++d) x[d] = gsum[t * 64 + d] / c;
  float acc = B2[0];
  for (int j = 0; j < 64; ++j) {
    float h = B1[j];
#pragma unroll
    for (int k = 0; k < 64; ++k) h += x[k] * w1s[j * 64 + k];
    acc += fmaxf(h, 0.f) * w2s[j];
  }
  outp[t] = 1.f / (1.f + __expf(-acc));
}

// ---------- launch ----------
extern "C" void kernel_launch(void* const* d_in, const int* in_sizes, int n_in,
                              void* d_out, int out_size, void* d_ws, size_t ws_size,
                              hipStream_t stream) {
  const int* le = (const int*)d_in[2];
  const int* ce = (const int*)d_in[3];
  const int* lb = (const int*)d_in[4];
  const float* l_init = (const float*)d_in[5];
  const float* c_init = (const float*)d_in[6];
  const float* l2c_W1 = (const float*)d_in[7];
  const float* l2c_b1 = (const float*)d_in[8];
  const float* l2c_W2 = (const float*)d_in[9];
  const float* l2c_b2 = (const float*)d_in[10];
  const float* c2l_W1 = (const float*)d_in[11];
  const float* c2l_b1 = (const float*)d_in[12];
  const float* c2l_W2 = (const float*)d_in[13];
  const float* c2l_b2 = (const float*)d_in[14];
  const float* gc_Wih = (const float*)d_in[15];
  const float* gc_Whh = (const float*)d_in[16];
  const float* gc_bih = (const float*)d_in[17];
  const float* gc_bhh = (const float*)d_in[18];
  const float* gl_Wih = (const float*)d_in[19];
  const float* gl_Whh = (const float*)d_in[20];
  const float* gl_bih = (const float*)d_in[21];
  const float* gl_bhh = (const float*)d_in[22];
  const float* ro_W1 = (const float*)d_in[23];
  const float* ro_b1 = (const float*)d_in[24];
  const float* ro_W2 = (const float*)d_in[25];
  const float* ro_b2 = (const float*)d_in[26];
  const int E = in_sizes[2];
  const int L = in_sizes[4];
  const int C = 100000;

  char* p = (char*)d_ws;
  auto alloc = [&](size_t b) -> char* {
    char* r = p;
    p += (b + 255) & ~(size_t)255;
    return r;
  };
  float* l_emb = (float*)alloc((size_t)L * 64 * 4);
  float* c_emb = (float*)alloc((size_t)C * 64 * 4);
  float* l_msg = (float*)alloc((size_t)L * 64 * 4);
  float* c_msg = (float*)alloc((size_t)C * 64 * 4);
  float* l2c_aggr = (float*)alloc((size_t)C * 64 * 4);
  float* c2l_aggr = (float*)alloc((size_t)L * 64 * 4);
  int* rowptrC = (int*)alloc((size_t)(C + 1) * 4);
  int* rowptrL = (int*)alloc((size_t)(L + 1) * 4);
  int* degC = (int*)alloc((size_t)C * 4);
  int* degL = (int*)alloc((size_t)L * 4);
  int* srcL2C = (int*)alloc((size_t)E * 4);
  int* srcC2L = (int*)alloc((size_t)E * 4);
  int* rankL = (int*)alloc((size_t)E * 4);
  int* rankC = (int*)alloc((size_t)E * 4);
  int* bsum = (int*)alloc(512 * 4);  // [0,256) C, [256,512) L
  float* gsum = (float*)alloc(128 * 64 * 4);
  float* gcnt = (float*)alloc(128 * 4);
  float* msgL0 = (float*)alloc(64 * 4);
  float* msgC0 = (float*)alloc(64 * 4);
  unsigned short* gGl = (unsigned short*)alloc(73728 * 2);
  unsigned short* gGc = (unsigned short*)alloc(49152 * 2);
  unsigned short* gMl = (unsigned short*)alloc(16384 * 2);
  unsigned short* gMc = (unsigned short*)alloc(16384 * 2);

  // weight prep (once per launch)
  prep_split<<<8, 256, 0, stream>>>(gl_Wih, gl_Whh, gc_Wih, gc_Whh,
                                    l2c_W1, l2c_W2, c2l_W1, c2l_W2,
                                    gGl, gGc, gMl, gMc);

  // CSR build (once per launch; reused by 14 aggregations)
  hipMemsetAsync(degC, 0, (size_t)C * 4, stream);
  hipMemsetAsync(degL, 0, (size_t)L * 4, stream);
  count_kernel<<<1024, 256, 0, stream>>>(le, ce, degL, degC, rankL, rankC, E);
  int chC = (C + 255) / 256, chL = (L + 255) / 256;
  scan_pass1<<<512, 256, 0, stream>>>(degC, bsum, C, chC, degL, bsum + 256, L, chL);
  scan_pass2<<<2, 256, 0, stream>>>(bsum, rowptrC + C, bsum + 256, rowptrL + L);
  scan_pass3<<<512, 256, 0, stream>>>(degC, bsum, rowptrC, C, chC,
                                      degL, bsum + 256, rowptrL, L, chL);
  fill_kernel<<<512, 256, 0, stream>>>(le, ce, rowptrL, rowptrC, rankL, rankC,
                                       srcL2C, srcC2L, E);

  init_emb2<<<1024, 256, 0, stream>>>(l_emb, c_emb, l_init, c_init, L * 64, C * 64);

  int TL = L >> 4, TC = C >> 4;
  // iteration 0: all embeddings identical -> aggr = deg * MLP(init)
  msg0_kernel<<<1, 128, 0, stream>>>(l_init, c_init, l2c_W1, l2c_b1, l2c_W2, l2c_b2,
                                     c2l_W1, c2l_b1, c2l_W2, c2l_b2, msgL0, msgC0);
  aggr0_kernel<<<1024, 256, 0, stream>>>(degC, degL, msgL0, msgC0,
                                         l2c_aggr, c2l_aggr, C, L);
  gru_fused<<<256, 512, 0, stream>>>(l2c_aggr, c_emb, gGc, gc_bih, gc_bhh, C, 64,
                                     c2l_aggr, l_emb, gGl, gl_bih, gl_bhh, L);
  for (int it = 1; it < 8; ++it) {
    mlp_kernel<<<768, 256, 0, stream>>>(l_emb, l_msg, TL, gMl, l2c_b1, l2c_b2,
                                        c_emb, c_msg, TC, gMc, c2l_b1, c2l_b2, 512);
    aggr_kernel<<<2048, 256, 0, stream>>>(l_msg, rowptrC, srcL2C, l2c_aggr, C,
                                          c_msg, rowptrL, srcC2L, c2l_aggr, L);
    gru_fused<<<256, 512, 0, stream>>>(l2c_aggr, c_emb, gGc, gc_bih, gc_bhh, C, 64,
                                       c2l_aggr, l_emb, gGl, gl_bih, gl_bhh, L);
  }

  hipMemsetAsync(gsum, 0, 128 * 64 * 4, stream);
  hipMemsetAsync(gcnt, 0, 128 * 4, stream);
  readout_sum<<<512, 256, 0, stream>>>(l_emb, lb, gsum, gcnt, L);
  final_kernel<<<1, 128, 0, stream>>>(gsum, gcnt, ro_W1, ro_b1, ro_W2, ro_b2,
                                      (float*)d_out);
}